// Round 1
// 1228.669 us; speedup vs baseline: 1.0469x; 1.0469x over previous
//
#include <hip/hip_runtime.h>
#include <hip/hip_bf16.h>
#include <math.h>

#define RREL 6
#define NN   50000
#define EE   200000
#define DD   768
#define HH   4
#define CC   64
#define HC   256
#define OO   64
#define MPAD 50176    // 196 * 256
#define SCAN_B 49     // ceil(NN/1024)
#define NT   12       // 768 / 64 K-tiles

typedef __attribute__((ext_vector_type(8))) short short8;
typedef __attribute__((ext_vector_type(4))) float f32x4;
typedef __attribute__((ext_vector_type(8))) unsigned short ushort8v;
typedef __attribute__((ext_vector_type(4))) unsigned short ushort4v;

__device__ __forceinline__ float b2f(unsigned short u) {
  return __uint_as_float(((unsigned)u) << 16);
}
__device__ __forceinline__ unsigned short f2b(float f) {
  __hip_bfloat16 h = __float2bfloat16(f);
  unsigned short u;
  __builtin_memcpy(&u, &h, 2);
  return u;
}

// global_load_lds, 16B/lane, wave-uniform LDS base + lane*16
__device__ __forceinline__ void gload16(const void* g, void* s) {
  typedef __attribute__((address_space(1))) void gvoid;
  typedef __attribute__((address_space(3))) void svoid;
  __builtin_amdgcn_global_load_lds((gvoid*)(unsigned long long)g,
                                   (svoid*)(unsigned long long)s, 16, 0, 0);
}

// ---------- x -> bf16 (8 elems/thread) ----------
__global__ __launch_bounds__(256) void k_cvt_x(const float* __restrict__ x,
                                               unsigned short* __restrict__ xb) {
  long t = (long)blockIdx.x * 256 + threadIdx.x;
  long base = t * 8;
  int row = (int)(base / DD);
  ushort8v o;
  if (row < NN) {
    float4 a = *(const float4*)(x + base);
    float4 b = *(const float4*)(x + base + 4);
    o[0] = f2b(a.x); o[1] = f2b(a.y); o[2] = f2b(a.z); o[3] = f2b(a.w);
    o[4] = f2b(b.x); o[5] = f2b(b.y); o[6] = f2b(b.z); o[7] = f2b(b.w);
  } else {
    o = (ushort8v)0;
  }
  *(ushort8v*)(xb + base) = o;
}

// ---------- LDS-tiled transpose: Wl|Wr [768][256] -> Wt[r*512+j][768] bf16 ----------
__global__ __launch_bounds__(256) void k_repack_w(const float* __restrict__ Wl,
                                                  const float* __restrict__ Wr,
                                                  unsigned short* __restrict__ Wt) {
  __shared__ float t[32][33];
  int k0 = blockIdx.x * 32, j0 = blockIdx.y * 32, r = blockIdx.z;
  int tx = threadIdx.x & 31, ty = threadIdx.x >> 5;
#pragma unroll
  for (int s = 0; s < 4; s++) {
    int k = k0 + ty + 8 * s, j = j0 + tx;
    float v = (j < HC) ? Wl[((long)r * DD + k) * HC + j]
                       : Wr[((long)r * DD + k) * HC + (j - HC)];
    t[ty + 8 * s][tx] = v;
  }
  __syncthreads();
#pragma unroll
  for (int s = 0; s < 4; s++) {
    int j = j0 + ty + 8 * s, k = k0 + tx;
    Wt[((long)r * 512 + j) * DD + k] = f2b(t[tx][ty + 8 * s]);
  }
}

// ---------- repack [Wrel;Wroot] -> Bt[r][64][K] bf16 ----------
__global__ void k_repack_gc(const float* __restrict__ Wrel, const float* __restrict__ Wroot,
                            unsigned short* __restrict__ Bt, int K) {
  int idx = blockIdx.x * blockDim.x + threadIdx.x;
  if (idx >= RREL * 64 * K) return;
  int k = idx % K;
  int o = (idx / K) % 64;
  int r = idx / (64 * K);
  int h = K >> 1;
  float v = (k < h) ? Wrel[((long)r * h + k) * 64 + o]
                    : Wroot[((long)r * h + (k - h)) * 64 + o];
  Bt[idx] = f2b(v);
}

// ---------- fused 256x256 8-phase GEMM (T2+T3+T4+T5): Yall[r][MPAD][512] = Xb @ Wt^T ----
// LDS layout: [row][slot] with slot ^= (row&7)  (16B slots, XOR swizzle).
// global_load_lds writes linearly (dest = base + lane*16); the swizzle is applied by
// permuting the GLOBAL source column-group per lane (rule: linear dest + inv-swz source
// + swz on read).  One counted vmcnt(4) per K-tile; never drained to 0 in steady state.
#define STAGE_A(HALF, TT)                                                              \
  if ((TT) < NT) {                                                                     \
    long ko = (long)(TT) * 128;                                                        \
    char* db = ldsA + (((TT) & 1) << 15);                                              \
    gload16(AgB + (long)((HALF) * 64 + rA) * 1536 + ko + xcol,                         \
            db + ((HALF) * 64) * 128 + wave * 1024);                                   \
    gload16(AgB + (long)((HALF) * 64 + 128 + rA) * 1536 + ko + xcol,                   \
            db + ((HALF) * 64 + 128) * 128 + wave * 1024);                             \
  }

#define STAGE_B(HALF, TT)                                                              \
  if ((TT) < NT) {                                                                     \
    long ko = (long)(TT) * 128;                                                        \
    char* db = ldsB + (((TT) & 1) << 15);                                              \
    gload16(BgB + (long)(rb0 + (HALF) * 32 + lane8) * 1536 + ko + xcol,                \
            db + (rb0 + (HALF) * 32) * 128);                                           \
    gload16(BgB + (long)(rb1 + (HALF) * 32 + lane8) * 1536 + ko + xcol,                \
            db + (rb1 + (HALF) * 32) * 128);                                           \
  }

#define RD_PA(MH)                                                                      \
  do {                                                                                 \
    _Pragma("unroll") for (int fi = 0; fi < 4; ++fi) {                                 \
      pa[fi][0] = *(const short8*)(Ard + ((MH) * 64 + fi * 16) * 128 + s0);            \
      pa[fi][1] = *(const short8*)(Ard + ((MH) * 64 + fi * 16) * 128 + s1);            \
    }                                                                                  \
  } while (0)

#define RD_PB(NH)                                                                      \
  do {                                                                                 \
    _Pragma("unroll") for (int fj = 0; fj < 2; ++fj) {                                 \
      pb[fj][0] = *(const short8*)(Brd + ((NH) * 32 + fj * 16) * 128 + s0);            \
      pb[fj][1] = *(const short8*)(Brd + ((NH) * 32 + fj * 16) * 128 + s1);            \
    }                                                                                  \
  } while (0)

#define MM8(MH, NH)                                                                    \
  do {                                                                                 \
    _Pragma("unroll") for (int fi = 0; fi < 4; ++fi)                                   \
    _Pragma("unroll") for (int fj = 0; fj < 2; ++fj) {                                 \
      f32x4 c = acc[(MH) * 4 + fi][(NH) * 2 + fj];                                     \
      c = __builtin_amdgcn_mfma_f32_16x16x32_bf16(pa[fi][0], pb[fj][0], c, 0, 0, 0);   \
      c = __builtin_amdgcn_mfma_f32_16x16x32_bf16(pa[fi][1], pb[fj][1], c, 0, 0, 0);   \
      acc[(MH) * 4 + fi][(NH) * 2 + fj] = c;                                           \
    }                                                                                  \
  } while (0)

__global__ __launch_bounds__(512, 2) void k_gemm(const short* __restrict__ A,
                                                 const short* __restrict__ Bt,
                                                 unsigned short* __restrict__ Yall) {
  __shared__ __align__(16) char ldsA[65536];   // 2 bufs x 256 rows x 128 B
  __shared__ __align__(16) char ldsB[65536];
  int tid = threadIdx.x;
  int wgid = blockIdx.x;                       // 2352 = 196*12, 2352 % 8 == 0
  int swz = (wgid & 7) * 294 + (wgid >> 3);    // bijective XCD swizzle
  int bm = swz / 12, bn = swz % 12;            // bn fastest: A panel L2-resident per XCD
  int lane = tid & 63, wave = tid >> 6;
  int warp_m = wave >> 2, warp_n = wave & 3;
  int wm = warp_m * 128, wn = warp_n * 64;
  int l16 = lane & 15, quad = lane >> 4;
  int gm0 = bm * 256;
  const char* AgB = (const char*)A + (long)gm0 * 1536;
  const char* BgB = (const char*)Bt + (long)bn * 256 * 1536;
  int rA = tid >> 3;                           // 0..63: staged row within 64-row issue
  int lane8 = lane >> 3;
  long xcol = (long)(((tid & 7) ^ (rA & 7)) * 16);  // pre-swizzled source col-group
  int rb0 = (wave >> 2) * 64 + (wave & 3) * 8;      // B stage row base (wave-uniform)
  int rb1 = rb0 + 128;
  int s0 = (quad ^ (l16 & 7)) * 16, s1 = s0 ^ 64;   // swizzled ds_read slot bytes
  f32x4 acc[8][4] = {};

  // prologue: tile0 fully + tile1 A-X,B-X; wait leaves 2 half-tiles (4 loads) in flight
  STAGE_A(0, 0); STAGE_B(0, 0); STAGE_A(1, 0); STAGE_B(1, 0);
  STAGE_A(0, 1); STAGE_B(0, 1);
  asm volatile("s_waitcnt vmcnt(4)" ::: "memory");
  __builtin_amdgcn_s_barrier();

  for (int t = 0; t < NT; ++t) {
    int bo = (t & 1) << 15;
    const char* Ard = ldsA + bo + (wm + l16) * 128;
    const char* Brd = ldsB + bo + (wn + l16) * 128;
    short8 pa[4][2], pb[2][2];
    // phase 0: quadrant (mh=0, nh=0); stage A-Y(t+1)
    STAGE_A(1, t + 1);
    RD_PA(0); RD_PB(0);
    __builtin_amdgcn_s_barrier();
    asm volatile("s_waitcnt lgkmcnt(0)" ::: "memory");
    __builtin_amdgcn_s_setprio(1); MM8(0, 0); __builtin_amdgcn_s_setprio(0);
    __builtin_amdgcn_s_barrier();
    // phase 1: quadrant (0,1); stage B-Y(t+1)
    STAGE_B(1, t + 1);
    RD_PB(1);
    __builtin_amdgcn_s_barrier();
    asm volatile("s_waitcnt lgkmcnt(0)" ::: "memory");
    __builtin_amdgcn_s_setprio(1); MM8(0, 1); __builtin_amdgcn_s_setprio(0);
    __builtin_amdgcn_s_barrier();
    // phase 2: quadrant (1,0); stage A-X(t+2) (A-X of this buf freed after phase 1)
    STAGE_A(0, t + 2);
    RD_PA(1); RD_PB(0);
    __builtin_amdgcn_s_barrier();
    asm volatile("s_waitcnt lgkmcnt(0)" ::: "memory");
    __builtin_amdgcn_s_setprio(1); MM8(1, 0); __builtin_amdgcn_s_setprio(0);
    __builtin_amdgcn_s_barrier();
    // phase 3: quadrant (1,1); stage B-X(t+2) (B-X freed after phase 2)
    STAGE_B(0, t + 2);
    RD_PB(1);
    __builtin_amdgcn_s_barrier();
    asm volatile("s_waitcnt lgkmcnt(0)" ::: "memory");
    __builtin_amdgcn_s_setprio(1); MM8(1, 1); __builtin_amdgcn_s_setprio(0);
    // per-wave counted wait + barrier ==> tile t+1 landed across ALL waves;
    // leaves A-X(t+2), B-X(t+2) (4 loads) in flight across the barrier.
    if (t < NT - 2)       asm volatile("s_waitcnt vmcnt(4)" ::: "memory");
    else if (t == NT - 2) asm volatile("s_waitcnt vmcnt(0)" ::: "memory");
    __builtin_amdgcn_s_barrier();
  }

  int rel = bn >> 1;
  unsigned short* Yr = Yall + (long)rel * MPAD * 512;
  int cb = (bn & 1) * 256 + wn;
#pragma unroll
  for (int i = 0; i < 8; ++i) {
    int rowb = gm0 + wm + (i >> 2) * 64 + (i & 3) * 16 + quad * 4;
#pragma unroll
    for (int j = 0; j < 4; ++j) {
      int col = cb + (j >> 1) * 32 + (j & 1) * 16 + l16;
#pragma unroll
      for (int reg = 0; reg < 4; ++reg)
        Yr[(long)(rowb + reg) * 512 + col] = f2b(acc[i][j][reg]);
    }
  }
}

// ---------- batched small-N MFMA GEMM for GraphConv (blockIdx.y = relation) ----------
template <int K, bool RELU, bool OBF16>
__global__ __launch_bounds__(256) void k_gcgemm(const short* __restrict__ Aall,
                                                const short* __restrict__ Btall,
                                                const float* __restrict__ biasall,
                                                void* __restrict__ outp, long ldo, int ocol,
                                                long orelstride) {
  __shared__ __align__(16) short As[128 * 32];
  __shared__ __align__(16) short Bs[64 * 32];
  int tid = threadIdx.x;
  int bm = blockIdx.x, r = blockIdx.y;
  const short* A  = Aall + (long)r * MPAD * K;
  const short* Bt = Btall + (long)r * 64 * K;
  const float* bias = biasall + (long)r * 64;
  int lane = tid & 63, wave = tid >> 6;
  int quad = lane >> 4, l16 = lane & 15;
  f32x4 acc[2][4] = {};
  const short* Ag = A + (long)bm * 128 * K;
  int lr = lane >> 2, lc = (lane & 3) * 8;
  const short* ga0 = Ag + (long)(wave * 16 + lr) * K + lc;
  const short* ga1 = Ag + (long)(64 + wave * 16 + lr) * K + lc;
  const short* gb0 = Bt + (long)(wave * 16 + lr) * K + lc;
  short* la0 = &As[(wave * 16) * 32];
  short* la1 = &As[(64 + wave * 16) * 32];
  short* lb0 = &Bs[(wave * 16) * 32];
  for (int k0 = 0; k0 < K; k0 += 32) {
    gload16(ga0 + k0, la0);
    gload16(ga1 + k0, la1);
    gload16(gb0 + k0, lb0);
    __syncthreads();
    short8 af[2], bf[4];
#pragma unroll
    for (int i = 0; i < 2; i++) af[i] = *(const short8*)&As[(wave * 32 + i * 16 + l16) * 32 + quad * 8];
#pragma unroll
    for (int j = 0; j < 4; j++) bf[j] = *(const short8*)&Bs[(j * 16 + l16) * 32 + quad * 8];
#pragma unroll
    for (int i = 0; i < 2; i++)
#pragma unroll
      for (int j = 0; j < 4; j++)
        acc[i][j] = __builtin_amdgcn_mfma_f32_16x16x32_bf16(af[i], bf[j], acc[i][j], 0, 0, 0);
    __syncthreads();
  }
#pragma unroll
  for (int i = 0; i < 2; i++)
#pragma unroll
    for (int j = 0; j < 4; j++)
#pragma unroll
      for (int reg = 0; reg < 4; reg++) {
        int row = bm * 128 + wave * 32 + i * 16 + quad * 4 + reg;
        int col = j * 16 + l16;
        float v = acc[i][j][reg] + bias[col];
        if (RELU) v = fmaxf(v, 0.f);
        if (OBF16) {
          ((unsigned short*)outp)[(long)r * orelstride + (long)row * ldo + ocol + col] = f2b(v);
        } else {
          if (row < NN) ((float*)outp)[(long)r * orelstride + (long)row * ldo + ocol + col] = v;
        }
      }
}

// ---------- batched CSR build ----------
__global__ void k_deg6(const int* __restrict__ ei, int* __restrict__ deg6) {
  long e = (long)blockIdx.x * blockDim.x + threadIdx.x;
  if (e >= (long)RREL * EE) return;
  int r = e / EE, i = e % EE;
  int t = ei[(long)r * 2 * EE + EE + i];
  atomicAdd(&deg6[(long)r * NN + t], 1);
}

__global__ __launch_bounds__(256) void k_bsum(const int* __restrict__ deg6, int* __restrict__ bsum) {
  int r = blockIdx.y, b = blockIdx.x, tid = threadIdx.x;
  const int* deg = deg6 + (long)r * NN;
  int i0 = b * 1024 + tid * 4;
  int s = 0;
#pragma unroll
  for (int j = 0; j < 4; j++) { int i = i0 + j; if (i < NN) s += deg[i]; }
#pragma unroll
  for (int m = 1; m < 64; m <<= 1) s += __shfl_xor(s, m);
  __shared__ int ws[4];
  if ((tid & 63) == 0) ws[tid >> 6] = s;
  __syncthreads();
  if (tid == 0) bsum[r * SCAN_B + b] = ws[0] + ws[1] + ws[2] + ws[3];
}

__global__ void k_bscan(int* __restrict__ bsum) {   // 1 block, 384 thr = 6 waves
  int w = threadIdx.x >> 6, l = threadIdx.x & 63;
  int v = (l < SCAN_B) ? bsum[w * SCAN_B + l] : 0;
  int incl = v;
#pragma unroll
  for (int d = 1; d < 64; d <<= 1) { int t = __shfl_up(incl, d); if (l >= d) incl += t; }
  if (l < SCAN_B) bsum[w * SCAN_B + l] = incl - v;   // exclusive
}

__global__ __launch_bounds__(256) void k_boff(const int* __restrict__ deg6, const int* __restrict__ bsum,
                                              int* __restrict__ off6, int* __restrict__ cur6) {
  int r = blockIdx.y, b = blockIdx.x, tid = threadIdx.x;
  const int* deg = deg6 + (long)r * NN;
  int i0 = b * 1024 + tid * 4;
  int v[4], s = 0;
#pragma unroll
  for (int j = 0; j < 4; j++) { int i = i0 + j; v[j] = (i < NN) ? deg[i] : 0; s += v[j]; }
  int l = tid & 63, wv = tid >> 6;
  int incl = s;
#pragma unroll
  for (int d = 1; d < 64; d <<= 1) { int t = __shfl_up(incl, d); if (l >= d) incl += t; }
  __shared__ int ws[4];
  if (l == 63) ws[wv] = incl;
  __syncthreads();
  int pre = incl - s;
  for (int k = 0; k < wv; k++) pre += ws[k];
  pre += bsum[r * SCAN_B + b];
  int e0 = pre;
#pragma unroll
  for (int j = 0; j < 4; j++) {
    int i = i0 + j;
    if (i < NN) { off6[(long)r * NN + i] = e0; cur6[(long)r * NN + i] = e0; }
    e0 += v[j];
  }
}

__global__ void k_scatter6(const int* __restrict__ ei, int* __restrict__ cur6,
                           int* __restrict__ ssrc6) {
  long e = (long)blockIdx.x * blockDim.x + threadIdx.x;
  if (e >= (long)RREL * EE) return;
  int r = e / EE, i = e % EE;
  int src = ei[(long)r * 2 * EE + i];
  int t   = ei[(long)r * 2 * EE + EE + i];
  int p = atomicAdd(&cur6[(long)r * NN + t], 1);
  ssrc6[(long)r * EE + p] = src;
}

// ---------- batched fused GATv2 (blockIdx.y = r); h1 overwrites Y[:,256:512] ----------
__global__ __launch_bounds__(256) void k_gat(unsigned short* __restrict__ Yall,
                                             const int* __restrict__ ssrc6,
                                             const int* __restrict__ off6, const int* __restrict__ deg6,
                                             const float* __restrict__ attall,
                                             const float* __restrict__ bgall) {
  int r = blockIdx.y;
  unsigned short* Y = Yall + (long)r * MPAD * 512;
  const int* ssrc = ssrc6 + (long)r * EE;
  const float* att = attall + r * HC;
  const float* bg  = bgall + r * HC;
  int l = threadIdx.x & 63;
  int n = blockIdx.x * 4 + (threadIdx.x >> 6);
  if (n >= NN) return;
  const unsigned short* yb = Y + (long)n * 512;
  ushort4v xlv = *(const ushort4v*)(yb + 4 * l);
  ushort4v xrv = *(const ushort4v*)(yb + 256 + 4 * l);
  float xl[4], xr[4];
#pragma unroll
  for (int j = 0; j < 4; j++) { xl[j] = b2f(xlv[j]); xr[j] = b2f(xrv[j]); }
  float4 at4 = *(const float4*)(att + 4 * l);
  float at[4] = {at4.x, at4.y, at4.z, at4.w};
  float num[4] = {0.f, 0.f, 0.f, 0.f}, den = 0.f;
  // self loop
  {
    float lg = 0.f;
#pragma unroll
    for (int j = 0; j < 4; j++) {
      float e = xl[j] + xr[j];
      e = e > 0.f ? e : 0.2f * e;
      lg += at[j] * e;
    }
    lg += __shfl_xor(lg, 1); lg += __shfl_xor(lg, 2);
    lg += __shfl_xor(lg, 4); lg += __shfl_xor(lg, 8);
    float a = expf(lg);
    den += a;
#pragma unroll
    for (int j = 0; j < 4; j++) num[j] += a * xl[j];
  }
  int st = off6[(long)r * NN + n], cnt = deg6[(long)r * NN + n];
  int i = 0;
  for (; i + 2 <= cnt; i += 2) {   // 2-way unroll: two gathers in flight
    int s0 = ssrc[st + i], s1 = ssrc[st + i + 1];
    ushort4v v0 = *(const ushort4v*)(Y + (long)s0 * 512 + 4 * l);
    ushort4v v1 = *(const ushort4v*)(Y + (long)s1 * 512 + 4 * l);
    float x0[4], x1[4];
#pragma unroll
    for (int j = 0; j < 4; j++) { x0[j] = b2f(v0[j]); x1[j] = b2f(v1[j]); }
    float lg0 = 0.f, lg1 = 0.f;
#pragma unroll
    for (int j = 0; j < 4; j++) {
      float e0 = x0[j] + xr[j]; e0 = e0 > 0.f ? e0 : 0.2f * e0; lg0 += at[j] * e0;
      float e1 = x1[j] + xr[j]; e1 = e1 > 0.f ? e1 : 0.2f * e1; lg1 += at[j] * e1;
    }
    lg0 += __shfl_xor(lg0, 1); lg1 += __shfl_xor(lg1, 1);
    lg0 += __shfl_xor(lg0, 2); lg1 += __shfl_xor(lg1, 2);
    lg0 += __shfl_xor(lg0, 4); lg1 += __shfl_xor(lg1, 4);
    lg0 += __shfl_xor(lg0, 8); lg1 += __shfl_xor(lg1, 8);
    float a0 = expf(lg0), a1 = expf(lg1);
    den += a0 + a1;
#pragma unroll
    for (int j = 0; j < 4; j++) num[j] += a0 * x0[j] + a1 * x1[j];
  }
  if (i < cnt) {
    int s0 = ssrc[st + i];
    ushort4v v0 = *(const ushort4v*)(Y + (long)s0 * 512 + 4 * l);
    float x0[4];
#pragma unroll
    for (int j = 0; j < 4; j++) x0[j] = b2f(v0[j]);
    float lg = 0.f;
#pragma unroll
    for (int j = 0; j < 4; j++) {
      float e = x0[j] + xr[j];
      e = e > 0.f ? e : 0.2f * e;
      lg += at[j] * e;
    }
    lg += __shfl_xor(lg, 1); lg += __shfl_xor(lg, 2);
    lg += __shfl_xor(lg, 4); lg += __shfl_xor(lg, 8);
    float a = expf(lg);
    den += a;
#pragma unroll
    for (int j = 0; j < 4; j++) num[j] += a * x0[j];
  }
  float4 bg4 = *(const float4*)(bg + 4 * l);
  float bgj[4] = {bg4.x, bg4.y, bg4.z, bg4.w};
  ushort4v o;
  float inv = 1.f / (den + 1e-16f);
#pragma unroll
  for (int j = 0; j < 4; j++) o[j] = f2b(fmaxf(num[j] * inv + bgj[j], 0.f));
  *(ushort4v*)(Y + (long)n * 512 + 256 + 4 * l) = o;   // h1 over dead xr
}

// ---------- batched CSR gather-sum of h1; agg over dead xl half ----------
__global__ __launch_bounds__(256) void k_agg1(unsigned short* __restrict__ Yall,
                                              const int* __restrict__ ssrc6,
                                              const int* __restrict__ off6,
                                              const int* __restrict__ deg6) {
  int r = blockIdx.y;
  unsigned short* Y = Yall + (long)r * MPAD * 512;
  const int* ssrc = ssrc6 + (long)r * EE;
  int l = threadIdx.x & 63;
  int n = blockIdx.x * 4 + (threadIdx.x >> 6);
  if (n >= NN) return;
  float acc[4] = {0.f, 0.f, 0.f, 0.f};
  int st = off6[(long)r * NN + n], cnt = deg6[(long)r * NN + n];
  int i = 0;
  for (; i + 4 <= cnt; i += 4) {
    int s0 = ssrc[st + i], s1 = ssrc[st + i + 1], s2 = ssrc[st + i + 2], s3 = ssrc[st + i + 3];
    ushort4v v0 = *(const ushort4v*)(Y + (long)s0 * 512 + 256 + 4 * l);
    ushort4v v1 = *(const ushort4v*)(Y + (long)s1 * 512 + 256 + 4 * l);
    ushort4v v2 = *(const ushort4v*)(Y + (long)s2 * 512 + 256 + 4 * l);
    ushort4v v3 = *(const ushort4v*)(Y + (long)s3 * 512 + 256 + 4 * l);
#pragma unroll
    for (int j = 0; j < 4; j++)
      acc[j] += b2f(v0[j]) + b2f(v1[j]) + b2f(v2[j]) + b2f(v3[j]);
  }
  for (; i < cnt; i++) {
    int s = ssrc[st + i];
    ushort4v v = *(const ushort4v*)(Y + (long)s * 512 + 256 + 4 * l);
#pragma unroll
    for (int j = 0; j < 4; j++) acc[j] += b2f(v[j]);
  }
  ushort4v o;
#pragma unroll
  for (int j = 0; j < 4; j++) o[j] = f2b(acc[j]);
  *(ushort4v*)(Y + (long)n * 512 + 4 * l) = o;
}

// ---------- batched CSR gather-sum of h2 ----------
__global__ __launch_bounds__(256) void k_agg2(unsigned short* __restrict__ ABall,
                                              const int* __restrict__ ssrc6,
                                              const int* __restrict__ off6,
                                              const int* __restrict__ deg6) {
  int r = blockIdx.y;
  unsigned short* AB2 = ABall + (long)r * MPAD * 128;
  const int* ssrc = ssrc6 + (long)r * EE;
  int l = threadIdx.x & 63;
  int n = blockIdx.x * 4 + (threadIdx.x >> 6);
  if (n >= NN) return;
  float acc = 0.f;
  int st = off6[(long)r * NN + n], cnt = deg6[(long)r * NN + n];
  int i = 0;
  for (; i + 4 <= cnt; i += 4) {
    int s0 = ssrc[st + i], s1 = ssrc[st + i + 1], s2 = ssrc[st + i + 2], s3 = ssrc[st + i + 3];
    acc += b2f(AB2[(long)s0 * 128 + OO + l]) + b2f(AB2[(long)s1 * 128 + OO + l]) +
           b2f(AB2[(long)s2 * 128 + OO + l]) + b2f(AB2[(long)s3 * 128 + OO + l]);
  }
  for (; i < cnt; i++) {
    int s = ssrc[st + i];
    acc += b2f(AB2[(long)s * 128 + OO + l]);
  }
  AB2[(long)n * 128 + l] = f2b(acc);
}

extern "C" void kernel_launch(void* const* d_in, const int* in_sizes, int n_in,
                              void* d_out, int out_size, void* d_ws, size_t ws_size,
                              hipStream_t stream) {
  (void)in_sizes; (void)n_in; (void)out_size;
  const float* x      = (const float*)d_in[0];
  const int*   ei     = (const int*)d_in[1];
  const float* Wl     = (const float*)d_in[2];
  const float* Wr     = (const float*)d_in[3];
  const float* att    = (const float*)d_in[4];
  const float* bg     = (const float*)d_in[5];
  const float* Wrel1  = (const float*)d_in[6];
  const float* Wroot1 = (const float*)d_in[7];
  const float* b1     = (const float*)d_in[8];
  const float* Wrel2  = (const float*)d_in[9];
  const float* Wroot2 = (const float*)d_in[10];
  const float* b2     = (const float*)d_in[11];
  float* out = (float*)d_out;

  char* ws = (char*)d_ws;
  size_t ofs = 0;
  auto alloc = [&](size_t bytes) {
    char* p = ws + ofs;
    ofs += (bytes + 255) & ~(size_t)255;
    return p;
  };
  unsigned short* Xb   = (unsigned short*)alloc((size_t)MPAD * DD * 2);
  unsigned short* Wt   = (unsigned short*)alloc((size_t)RREL * 512 * DD * 2);
  unsigned short* Wt1  = (unsigned short*)alloc((size_t)RREL * 64 * 512 * 2);
  unsigned short* Wt2  = (unsigned short*)alloc((size_t)RREL * 64 * 128 * 2);
  unsigned short* Yall = (unsigned short*)alloc((size_t)RREL * MPAD * 512 * 2);  // 308 MB
  unsigned short* AB2  = (unsigned short*)alloc((size_t)RREL * MPAD * 128 * 2);  // 77 MB
  int* deg6   = (int*)alloc((size_t)RREL * NN * 4);
  int* off6   = (int*)alloc((size_t)RREL * NN * 4);
  int* cur6   = (int*)alloc((size_t)RREL * NN * 4);
  int* bsum   = (int*)alloc((size_t)RREL * SCAN_B * 4);
  int* ssrc6  = (int*)alloc((size_t)RREL * EE * 4);
  if (ofs > ws_size) return;

  k_cvt_x<<<(int)((long)MPAD * DD / 8 / 256), 256, 0, stream>>>(x, Xb);
  k_repack_w<<<dim3(DD / 32, 512 / 32, RREL), 256, 0, stream>>>(Wl, Wr, Wt);
  k_repack_gc<<<(RREL * 64 * 512 + 255) / 256, 256, 0, stream>>>(Wrel1, Wroot1, Wt1, 512);
  k_repack_gc<<<(RREL * 64 * 128 + 255) / 256, 256, 0, stream>>>(Wrel2, Wroot2, Wt2, 128);
  hipMemsetAsync(deg6, 0, (size_t)RREL * NN * 4, stream);
  k_deg6<<<((long)RREL * EE + 255) / 256, 256, 0, stream>>>(ei, deg6);
  k_bsum<<<dim3(SCAN_B, RREL), 256, 0, stream>>>(deg6, bsum);
  k_bscan<<<1, 384, 0, stream>>>(bsum);
  k_boff<<<dim3(SCAN_B, RREL), 256, 0, stream>>>(deg6, bsum, off6, cur6);
  k_scatter6<<<((long)RREL * EE + 255) / 256, 256, 0, stream>>>(ei, cur6, ssrc6);

  // one fused 8-phase GEMM: all relations, all 3072 output columns
  k_gemm<<<dim3(196 * 12), 512, 0, stream>>>((const short*)Xb, (const short*)Wt, Yall);
  // batched edge + gc stages (blockIdx.y = relation)
  k_gat<<<dim3(NN / 4, RREL), 256, 0, stream>>>(Yall, ssrc6, off6, deg6, att, bg);
  k_agg1<<<dim3(NN / 4, RREL), 256, 0, stream>>>(Yall, ssrc6, off6, deg6);
  k_gcgemm<512, true, true><<<dim3(MPAD / 128, RREL), 256, 0, stream>>>(
      (const short*)Yall, (const short*)Wt1, b1, (void*)AB2, 128, OO, (long)MPAD * 128);
  k_agg2<<<dim3(NN / 4, RREL), 256, 0, stream>>>(AB2, ssrc6, off6, deg6);
  k_gcgemm<128, false, false><<<dim3(MPAD / 128, RREL), 256, 0, stream>>>(
      (const short*)AB2, (const short*)Wt2, b2, (void*)out, RREL * OO, 0, 64);
}

// Round 2
// 1225.967 us; speedup vs baseline: 1.0492x; 1.0022x over previous
//
#include <hip/hip_runtime.h>
#include <hip/hip_bf16.h>
#include <math.h>

#define RREL 6
#define NN   50000
#define EE   200000
#define DD   768
#define HH   4
#define CC   64
#define HC   256
#define OO   64
#define MPAD 50176    // 196 * 256
#define SCAN_B 49     // ceil(NN/1024)
#define NT   12       // 768 / 64 K-tiles

typedef __attribute__((ext_vector_type(8))) short short8;
typedef __attribute__((ext_vector_type(4))) float f32x4;
typedef __attribute__((ext_vector_type(8))) unsigned short ushort8v;
typedef __attribute__((ext_vector_type(4))) unsigned short ushort4v;

__device__ __forceinline__ float b2f(unsigned short u) {
  return __uint_as_float(((unsigned)u) << 16);
}
__device__ __forceinline__ unsigned short f2b(float f) {
  __hip_bfloat16 h = __float2bfloat16(f);
  unsigned short u;
  __builtin_memcpy(&u, &h, 2);
  return u;
}

// global_load_lds, 16B/lane, wave-uniform LDS base + lane*16
__device__ __forceinline__ void gload16(const void* g, void* s) {
  typedef __attribute__((address_space(1))) void gvoid;
  typedef __attribute__((address_space(3))) void svoid;
  __builtin_amdgcn_global_load_lds((gvoid*)(unsigned long long)g,
                                   (svoid*)(unsigned long long)s, 16, 0, 0);
}

// ---------- x -> bf16 (8 elems/thread) ----------
__global__ __launch_bounds__(256) void k_cvt_x(const float* __restrict__ x,
                                               unsigned short* __restrict__ xb) {
  long t = (long)blockIdx.x * 256 + threadIdx.x;
  long base = t * 8;
  int row = (int)(base / DD);
  ushort8v o;
  if (row < NN) {
    float4 a = *(const float4*)(x + base);
    float4 b = *(const float4*)(x + base + 4);
    o[0] = f2b(a.x); o[1] = f2b(a.y); o[2] = f2b(a.z); o[3] = f2b(a.w);
    o[4] = f2b(b.x); o[5] = f2b(b.y); o[6] = f2b(b.z); o[7] = f2b(b.w);
  } else {
    o = (ushort8v)0;
  }
  *(ushort8v*)(xb + base) = o;
}

// ---------- LDS-tiled transpose: Wl|Wr [768][256] -> Wt[r*512+j][768] bf16 ----------
__global__ __launch_bounds__(256) void k_repack_w(const float* __restrict__ Wl,
                                                  const float* __restrict__ Wr,
                                                  unsigned short* __restrict__ Wt) {
  __shared__ float t[32][33];
  int k0 = blockIdx.x * 32, j0 = blockIdx.y * 32, r = blockIdx.z;
  int tx = threadIdx.x & 31, ty = threadIdx.x >> 5;
#pragma unroll
  for (int s = 0; s < 4; s++) {
    int k = k0 + ty + 8 * s, j = j0 + tx;
    float v = (j < HC) ? Wl[((long)r * DD + k) * HC + j]
                       : Wr[((long)r * DD + k) * HC + (j - HC)];
    t[ty + 8 * s][tx] = v;
  }
  __syncthreads();
#pragma unroll
  for (int s = 0; s < 4; s++) {
    int j = j0 + ty + 8 * s, k = k0 + tx;
    Wt[((long)r * 512 + j) * DD + k] = f2b(t[tx][ty + 8 * s]);
  }
}

// ---------- repack [Wrel;Wroot] -> Bt[r][64][K] bf16 ----------
__global__ void k_repack_gc(const float* __restrict__ Wrel, const float* __restrict__ Wroot,
                            unsigned short* __restrict__ Bt, int K) {
  int idx = blockIdx.x * blockDim.x + threadIdx.x;
  if (idx >= RREL * 64 * K) return;
  int k = idx % K;
  int o = (idx / K) % 64;
  int r = idx / (64 * K);
  int h = K >> 1;
  float v = (k < h) ? Wrel[((long)r * h + k) * 64 + o]
                    : Wroot[((long)r * h + (k - h)) * 64 + o];
  Bt[idx] = f2b(v);
}

// ---------- fused 256x256 8-phase GEMM (T2+T3+T4+T5): Yall[r][MPAD][512] = Xb @ Wt^T ----
// K-loop identical to the verified previous round.  Epilogue reworked: C tile staged
// into the (dead) 128 KiB LDS with a row-rotated layout (rotation = row*16 B so quads
// hit disjoint bank sets), then written out as full 64B-line coalesced 16B/lane stores.
#define STAGE_A(HALF, TT)                                                              \
  if ((TT) < NT) {                                                                     \
    long ko = (long)(TT) * 128;                                                        \
    char* db = ldsA + (((TT) & 1) << 15);                                              \
    gload16(AgB + (long)((HALF) * 64 + rA) * 1536 + ko + xcol,                         \
            db + ((HALF) * 64) * 128 + wave * 1024);                                   \
    gload16(AgB + (long)((HALF) * 64 + 128 + rA) * 1536 + ko + xcol,                   \
            db + ((HALF) * 64 + 128) * 128 + wave * 1024);                             \
  }

#define STAGE_B(HALF, TT)                                                              \
  if ((TT) < NT) {                                                                     \
    long ko = (long)(TT) * 128;                                                        \
    char* db = ldsB + (((TT) & 1) << 15);                                              \
    gload16(BgB + (long)(rb0 + (HALF) * 32 + lane8) * 1536 + ko + xcol,                \
            db + (rb0 + (HALF) * 32) * 128);                                           \
    gload16(BgB + (long)(rb1 + (HALF) * 32 + lane8) * 1536 + ko + xcol,                \
            db + (rb1 + (HALF) * 32) * 128);                                           \
  }

#define RD_PA(MH)                                                                      \
  do {                                                                                 \
    _Pragma("unroll") for (int fi = 0; fi < 4; ++fi) {                                 \
      pa[fi][0] = *(const short8*)(Ard + ((MH) * 64 + fi * 16) * 128 + s0);            \
      pa[fi][1] = *(const short8*)(Ard + ((MH) * 64 + fi * 16) * 128 + s1);            \
    }                                                                                  \
  } while (0)

#define RD_PB(NH)                                                                      \
  do {                                                                                 \
    _Pragma("unroll") for (int fj = 0; fj < 2; ++fj) {                                 \
      pb[fj][0] = *(const short8*)(Brd + ((NH) * 32 + fj * 16) * 128 + s0);            \
      pb[fj][1] = *(const short8*)(Brd + ((NH) * 32 + fj * 16) * 128 + s1);            \
    }                                                                                  \
  } while (0)

#define MM8(MH, NH)                                                                    \
  do {                                                                                 \
    _Pragma("unroll") for (int fi = 0; fi < 4; ++fi)                                   \
    _Pragma("unroll") for (int fj = 0; fj < 2; ++fj) {                                 \
      f32x4 c = acc[(MH) * 4 + fi][(NH) * 2 + fj];                                     \
      c = __builtin_amdgcn_mfma_f32_16x16x32_bf16(pa[fi][0], pb[fj][0], c, 0, 0, 0);   \
      c = __builtin_amdgcn_mfma_f32_16x16x32_bf16(pa[fi][1], pb[fj][1], c, 0, 0, 0);   \
      acc[(MH) * 4 + fi][(NH) * 2 + fj] = c;                                           \
    }                                                                                  \
  } while (0)

__global__ __launch_bounds__(512, 2) void k_gemm(const short* __restrict__ A,
                                                 const short* __restrict__ Bt,
                                                 unsigned short* __restrict__ Yall) {
  __shared__ __align__(16) char lds[131072];   // A: 2x32KB | B: 2x32KB; reused as C tile
  char* ldsA = lds;
  char* ldsB = lds + 65536;
  int tid = threadIdx.x;
  int wgid = blockIdx.x;                       // 2352 = 196*12, 2352 % 8 == 0
  int swz = (wgid & 7) * 294 + (wgid >> 3);    // bijective XCD swizzle
  int bm = swz / 12, bn = swz % 12;            // bn fastest: A panel L2-resident per XCD
  int lane = tid & 63, wave = tid >> 6;
  int warp_m = wave >> 2, warp_n = wave & 3;
  int wm = warp_m * 128, wn = warp_n * 64;
  int l16 = lane & 15, quad = lane >> 4;
  int gm0 = bm * 256;
  const char* AgB = (const char*)A + (long)gm0 * 1536;
  const char* BgB = (const char*)Bt + (long)bn * 256 * 1536;
  int rA = tid >> 3;                           // 0..63: staged row within 64-row issue
  int lane8 = lane >> 3;
  long xcol = (long)(((tid & 7) ^ (rA & 7)) * 16);  // pre-swizzled source col-group
  int rb0 = (wave >> 2) * 64 + (wave & 3) * 8;      // B stage row base (wave-uniform)
  int rb1 = rb0 + 128;
  int s0 = (quad ^ (l16 & 7)) * 16, s1 = s0 ^ 64;   // swizzled ds_read slot bytes
  f32x4 acc[8][4] = {};

  // prologue: tile0 fully + tile1 A-X,B-X; wait leaves 2 half-tiles (4 loads) in flight
  STAGE_A(0, 0); STAGE_B(0, 0); STAGE_A(1, 0); STAGE_B(1, 0);
  STAGE_A(0, 1); STAGE_B(0, 1);
  asm volatile("s_waitcnt vmcnt(4)" ::: "memory");
  __builtin_amdgcn_s_barrier();

  for (int t = 0; t < NT; ++t) {
    int bo = (t & 1) << 15;
    const char* Ard = ldsA + bo + (wm + l16) * 128;
    const char* Brd = ldsB + bo + (wn + l16) * 128;
    short8 pa[4][2], pb[2][2];
    // phase 0: quadrant (mh=0, nh=0); stage A-Y(t+1)
    STAGE_A(1, t + 1);
    RD_PA(0); RD_PB(0);
    __builtin_amdgcn_s_barrier();
    asm volatile("s_waitcnt lgkmcnt(0)" ::: "memory");
    __builtin_amdgcn_s_setprio(1); MM8(0, 0); __builtin_amdgcn_s_setprio(0);
    __builtin_amdgcn_s_barrier();
    // phase 1: quadrant (0,1); stage B-Y(t+1)
    STAGE_B(1, t + 1);
    RD_PB(1);
    __builtin_amdgcn_s_barrier();
    asm volatile("s_waitcnt lgkmcnt(0)" ::: "memory");
    __builtin_amdgcn_s_setprio(1); MM8(0, 1); __builtin_amdgcn_s_setprio(0);
    __builtin_amdgcn_s_barrier();
    // phase 2: quadrant (1,0); stage A-X(t+2) (A-X of this buf freed after phase 1)
    STAGE_A(0, t + 2);
    RD_PA(1); RD_PB(0);
    __builtin_amdgcn_s_barrier();
    asm volatile("s_waitcnt lgkmcnt(0)" ::: "memory");
    __builtin_amdgcn_s_setprio(1); MM8(1, 0); __builtin_amdgcn_s_setprio(0);
    __builtin_amdgcn_s_barrier();
    // phase 3: quadrant (1,1); stage B-X(t+2) (B-X freed after phase 2)
    STAGE_B(0, t + 2);
    RD_PB(1);
    __builtin_amdgcn_s_barrier();
    asm volatile("s_waitcnt lgkmcnt(0)" ::: "memory");
    __builtin_amdgcn_s_setprio(1); MM8(1, 1); __builtin_amdgcn_s_setprio(0);
    // per-wave counted wait + barrier ==> tile t+1 landed across ALL waves;
    // leaves A-X(t+2), B-X(t+2) (4 loads) in flight across the barrier.
    if (t < NT - 2)       asm volatile("s_waitcnt vmcnt(4)" ::: "memory");
    else if (t == NT - 2) asm volatile("s_waitcnt vmcnt(0)" ::: "memory");
    __builtin_amdgcn_s_barrier();
  }

  // ---- epilogue: stage C (256x256 bf16 = 128 KiB) into dead LDS, then coalesced out.
  // LDS layout: byte addr = row*512 + ((col*2 + row*16) & 511).  The row*16 rotation
  // puts the 4 quads (rows +0,+4,+8,+12) on bank sets {0-7,16-23,0-7,16-23} -> <=2-way.
#pragma unroll
  for (int i = 0; i < 8; ++i) {
    int rl = wm + (i >> 2) * 64 + (i & 3) * 16 + quad * 4;
#pragma unroll
    for (int j = 0; j < 4; ++j) {
      int cl2 = (wn + (j >> 1) * 32 + (j & 1) * 16 + l16) * 2;
#pragma unroll
      for (int reg = 0; reg < 4; ++reg) {
        int row = rl + reg;
        *(unsigned short*)(lds + row * 512 + ((cl2 + row * 16) & 511)) = f2b(acc[i][j][reg]);
      }
    }
  }
  __syncthreads();
  int rel = bn >> 1;
  char* Yb = (char*)(Yall + (long)rel * MPAD * 512) + (long)gm0 * 1024 + (long)((bn & 1) * 256) * 2;
  int bcol = (tid & 31) * 16;
  int r0 = tid >> 5;                       // 0..15
#pragma unroll
  for (int it = 0; it < 16; ++it) {
    int rl = r0 + it * 16;
    ushort8v v = *(const ushort8v*)(lds + rl * 512 + ((bcol + rl * 16) & 511));
    *(ushort8v*)(Yb + (long)rl * 1024 + bcol) = v;
  }
}

// ---------- batched small-N MFMA GEMM for GraphConv (blockIdx.y = relation) ----------
template <int K, bool RELU, bool OBF16>
__global__ __launch_bounds__(256) void k_gcgemm(const short* __restrict__ Aall,
                                                const short* __restrict__ Btall,
                                                const float* __restrict__ biasall,
                                                void* __restrict__ outp, long ldo, int ocol,
                                                long orelstride) {
  __shared__ __align__(16) short As[128 * 32];
  __shared__ __align__(16) short Bs[64 * 32];
  int tid = threadIdx.x;
  int bm = blockIdx.x, r = blockIdx.y;
  const short* A  = Aall + (long)r * MPAD * K;
  const short* Bt = Btall + (long)r * 64 * K;
  const float* bias = biasall + (long)r * 64;
  int lane = tid & 63, wave = tid >> 6;
  int quad = lane >> 4, l16 = lane & 15;
  f32x4 acc[2][4] = {};
  const short* Ag = A + (long)bm * 128 * K;
  int lr = lane >> 2, lc = (lane & 3) * 8;
  const short* ga0 = Ag + (long)(wave * 16 + lr) * K + lc;
  const short* ga1 = Ag + (long)(64 + wave * 16 + lr) * K + lc;
  const short* gb0 = Bt + (long)(wave * 16 + lr) * K + lc;
  short* la0 = &As[(wave * 16) * 32];
  short* la1 = &As[(64 + wave * 16) * 32];
  short* lb0 = &Bs[(wave * 16) * 32];
  for (int k0 = 0; k0 < K; k0 += 32) {
    gload16(ga0 + k0, la0);
    gload16(ga1 + k0, la1);
    gload16(gb0 + k0, lb0);
    __syncthreads();
    short8 af[2], bf[4];
#pragma unroll
    for (int i = 0; i < 2; i++) af[i] = *(const short8*)&As[(wave * 32 + i * 16 + l16) * 32 + quad * 8];
#pragma unroll
    for (int j = 0; j < 4; j++) bf[j] = *(const short8*)&Bs[(j * 16 + l16) * 32 + quad * 8];
#pragma unroll
    for (int i = 0; i < 2; i++)
#pragma unroll
      for (int j = 0; j < 4; j++)
        acc[i][j] = __builtin_amdgcn_mfma_f32_16x16x32_bf16(af[i], bf[j], acc[i][j], 0, 0, 0);
    __syncthreads();
  }
#pragma unroll
  for (int i = 0; i < 2; i++)
#pragma unroll
    for (int j = 0; j < 4; j++)
#pragma unroll
      for (int reg = 0; reg < 4; reg++) {
        int row = bm * 128 + wave * 32 + i * 16 + quad * 4 + reg;
        int col = j * 16 + l16;
        float v = acc[i][j][reg] + bias[col];
        if (RELU) v = fmaxf(v, 0.f);
        if (OBF16) {
          ((unsigned short*)outp)[(long)r * orelstride + (long)row * ldo + ocol + col] = f2b(v);
        } else {
          if (row < NN) ((float*)outp)[(long)r * orelstride + (long)row * ldo + ocol + col] = v;
        }
      }
}

// ---------- batched CSR build ----------
__global__ void k_deg6(const int* __restrict__ ei, int* __restrict__ deg6) {
  long e = (long)blockIdx.x * blockDim.x + threadIdx.x;
  if (e >= (long)RREL * EE) return;
  int r = e / EE, i = e % EE;
  int t = ei[(long)r * 2 * EE + EE + i];
  atomicAdd(&deg6[(long)r * NN + t], 1);
}

__global__ __launch_bounds__(256) void k_bsum(const int* __restrict__ deg6, int* __restrict__ bsum) {
  int r = blockIdx.y, b = blockIdx.x, tid = threadIdx.x;
  const int* deg = deg6 + (long)r * NN;
  int i0 = b * 1024 + tid * 4;
  int s = 0;
#pragma unroll
  for (int j = 0; j < 4; j++) { int i = i0 + j; if (i < NN) s += deg[i]; }
#pragma unroll
  for (int m = 1; m < 64; m <<= 1) s += __shfl_xor(s, m);
  __shared__ int ws[4];
  if ((tid & 63) == 0) ws[tid >> 6] = s;
  __syncthreads();
  if (tid == 0) bsum[r * SCAN_B + b] = ws[0] + ws[1] + ws[2] + ws[3];
}

__global__ void k_bscan(int* __restrict__ bsum) {   // 1 block, 384 thr = 6 waves
  int w = threadIdx.x >> 6, l = threadIdx.x & 63;
  int v = (l < SCAN_B) ? bsum[w * SCAN_B + l] : 0;
  int incl = v;
#pragma unroll
  for (int d = 1; d < 64; d <<= 1) { int t = __shfl_up(incl, d); if (l >= d) incl += t; }
  if (l < SCAN_B) bsum[w * SCAN_B + l] = incl - v;   // exclusive
}

__global__ __launch_bounds__(256) void k_boff(const int* __restrict__ deg6, const int* __restrict__ bsum,
                                              int* __restrict__ off6, int* __restrict__ cur6) {
  int r = blockIdx.y, b = blockIdx.x, tid = threadIdx.x;
  const int* deg = deg6 + (long)r * NN;
  int i0 = b * 1024 + tid * 4;
  int v[4], s = 0;
#pragma unroll
  for (int j = 0; j < 4; j++) { int i = i0 + j; v[j] = (i < NN) ? deg[i] : 0; s += v[j]; }
  int l = tid & 63, wv = tid >> 6;
  int incl = s;
#pragma unroll
  for (int d = 1; d < 64; d <<= 1) { int t = __shfl_up(incl, d); if (l >= d) incl += t; }
  __shared__ int ws[4];
  if (l == 63) ws[wv] = incl;
  __syncthreads();
  int pre = incl - s;
  for (int k = 0; k < wv; k++) pre += ws[k];
  pre += bsum[r * SCAN_B + b];
  int e0 = pre;
#pragma unroll
  for (int j = 0; j < 4; j++) {
    int i = i0 + j;
    if (i < NN) { off6[(long)r * NN + i] = e0; cur6[(long)r * NN + i] = e0; }
    e0 += v[j];
  }
}

__global__ void k_scatter6(const int* __restrict__ ei, int* __restrict__ cur6,
                           int* __restrict__ ssrc6) {
  long e = (long)blockIdx.x * blockDim.x + threadIdx.x;
  if (e >= (long)RREL * EE) return;
  int r = e / EE, i = e % EE;
  int src = ei[(long)r * 2 * EE + i];
  int t   = ei[(long)r * 2 * EE + EE + i];
  int p = atomicAdd(&cur6[(long)r * NN + t], 1);
  ssrc6[(long)r * EE + p] = src;
}

// ---------- batched fused GATv2 (blockIdx.y = r); h1 overwrites Y[:,256:512] ----------
__global__ __launch_bounds__(256) void k_gat(unsigned short* __restrict__ Yall,
                                             const int* __restrict__ ssrc6,
                                             const int* __restrict__ off6, const int* __restrict__ deg6,
                                             const float* __restrict__ attall,
                                             const float* __restrict__ bgall) {
  int r = blockIdx.y;
  unsigned short* Y = Yall + (long)r * MPAD * 512;
  const int* ssrc = ssrc6 + (long)r * EE;
  const float* att = attall + r * HC;
  const float* bg  = bgall + r * HC;
  int l = threadIdx.x & 63;
  int n = blockIdx.x * 4 + (threadIdx.x >> 6);
  if (n >= NN) return;
  const unsigned short* yb = Y + (long)n * 512;
  ushort4v xlv = *(const ushort4v*)(yb + 4 * l);
  ushort4v xrv = *(const ushort4v*)(yb + 256 + 4 * l);
  float xl[4], xr[4];
#pragma unroll
  for (int j = 0; j < 4; j++) { xl[j] = b2f(xlv[j]); xr[j] = b2f(xrv[j]); }
  float4 at4 = *(const float4*)(att + 4 * l);
  float at[4] = {at4.x, at4.y, at4.z, at4.w};
  float num[4] = {0.f, 0.f, 0.f, 0.f}, den = 0.f;
  // self loop
  {
    float lg = 0.f;
#pragma unroll
    for (int j = 0; j < 4; j++) {
      float e = xl[j] + xr[j];
      e = e > 0.f ? e : 0.2f * e;
      lg += at[j] * e;
    }
    lg += __shfl_xor(lg, 1); lg += __shfl_xor(lg, 2);
    lg += __shfl_xor(lg, 4); lg += __shfl_xor(lg, 8);
    float a = expf(lg);
    den += a;
#pragma unroll
    for (int j = 0; j < 4; j++) num[j] += a * xl[j];
  }
  int st = off6[(long)r * NN + n], cnt = deg6[(long)r * NN + n];
  int i = 0;
  for (; i + 2 <= cnt; i += 2) {   // 2-way unroll: two gathers in flight
    int s0 = ssrc[st + i], s1 = ssrc[st + i + 1];
    ushort4v v0 = *(const ushort4v*)(Y + (long)s0 * 512 + 4 * l);
    ushort4v v1 = *(const ushort4v*)(Y + (long)s1 * 512 + 4 * l);
    float x0[4], x1[4];
#pragma unroll
    for (int j = 0; j < 4; j++) { x0[j] = b2f(v0[j]); x1[j] = b2f(v1[j]); }
    float lg0 = 0.f, lg1 = 0.f;
#pragma unroll
    for (int j = 0; j < 4; j++) {
      float e0 = x0[j] + xr[j]; e0 = e0 > 0.f ? e0 : 0.2f * e0; lg0 += at[j] * e0;
      float e1 = x1[j] + xr[j]; e1 = e1 > 0.f ? e1 : 0.2f * e1; lg1 += at[j] * e1;
    }
    lg0 += __shfl_xor(lg0, 1); lg1 += __shfl_xor(lg1, 1);
    lg0 += __shfl_xor(lg0, 2); lg1 += __shfl_xor(lg1, 2);
    lg0 += __shfl_xor(lg0, 4); lg1 += __shfl_xor(lg1, 4);
    lg0 += __shfl_xor(lg0, 8); lg1 += __shfl_xor(lg1, 8);
    float a0 = expf(lg0), a1 = expf(lg1);
    den += a0 + a1;
#pragma unroll
    for (int j = 0; j < 4; j++) num[j] += a0 * x0[j] + a1 * x1[j];
  }
  if (i < cnt) {
    int s0 = ssrc[st + i];
    ushort4v v0 = *(const ushort4v*)(Y + (long)s0 * 512 + 4 * l);
    float x0[4];
#pragma unroll
    for (int j = 0; j < 4; j++) x0[j] = b2f(v0[j]);
    float lg = 0.f;
#pragma unroll
    for (int j = 0; j < 4; j++) {
      float e = x0[j] + xr[j];
      e = e > 0.f ? e : 0.2f * e;
      lg += at[j] * e;
    }
    lg += __shfl_xor(lg, 1); lg += __shfl_xor(lg, 2);
    lg += __shfl_xor(lg, 4); lg += __shfl_xor(lg, 8);
    float a = expf(lg);
    den += a;
#pragma unroll
    for (int j = 0; j < 4; j++) num[j] += a * x0[j];
  }
  float4 bg4 = *(const float4*)(bg + 4 * l);
  float bgj[4] = {bg4.x, bg4.y, bg4.z, bg4.w};
  ushort4v o;
  float inv = 1.f / (den + 1e-16f);
#pragma unroll
  for (int j = 0; j < 4; j++) o[j] = f2b(fmaxf(num[j] * inv + bgj[j], 0.f));
  *(ushort4v*)(Y + (long)n * 512 + 256 + 4 * l) = o;   // h1 over dead xr
}

// ---------- batched CSR gather-sum of h1; agg over dead xl half ----------
__global__ __launch_bounds__(256) void k_agg1(unsigned short* __restrict__ Yall,
                                              const int* __restrict__ ssrc6,
                                              const int* __restrict__ off6,
                                              const int* __restrict__ deg6) {
  int r = blockIdx.y;
  unsigned short* Y = Yall + (long)r * MPAD * 512;
  const int* ssrc = ssrc6 + (long)r * EE;
  int l = threadIdx.x & 63;
  int n = blockIdx.x * 4 + (threadIdx.x >> 6);
  if (n >= NN) return;
  float acc[4] = {0.f, 0.f, 0.f, 0.f};
  int st = off6[(long)r * NN + n], cnt = deg6[(long)r * NN + n];
  int i = 0;
  for (; i + 4 <= cnt; i += 4) {
    int s0 = ssrc[st + i], s1 = ssrc[st + i + 1], s2 = ssrc[st + i + 2], s3 = ssrc[st + i + 3];
    ushort4v v0 = *(const ushort4v*)(Y + (long)s0 * 512 + 256 + 4 * l);
    ushort4v v1 = *(const ushort4v*)(Y + (long)s1 * 512 + 256 + 4 * l);
    ushort4v v2 = *(const ushort4v*)(Y + (long)s2 * 512 + 256 + 4 * l);
    ushort4v v3 = *(const ushort4v*)(Y + (long)s3 * 512 + 256 + 4 * l);
#pragma unroll
    for (int j = 0; j < 4; j++)
      acc[j] += b2f(v0[j]) + b2f(v1[j]) + b2f(v2[j]) + b2f(v3[j]);
  }
  for (; i < cnt; i++) {
    int s = ssrc[st + i];
    ushort4v v = *(const ushort4v*)(Y + (long)s * 512 + 256 + 4 * l);
#pragma unroll
    for (int j = 0; j < 4; j++) acc[j] += b2f(v[j]);
  }
  ushort4v o;
#pragma unroll
  for (int j = 0; j < 4; j++) o[j] = f2b(acc[j]);
  *(ushort4v*)(Y + (long)n * 512 + 4 * l) = o;
}

// ---------- batched CSR gather-sum of h2 ----------
__global__ __launch_bounds__(256) void k_agg2(unsigned short* __restrict__ ABall,
                                              const int* __restrict__ ssrc6,
                                              const int* __restrict__ off6,
                                              const int* __restrict__ deg6) {
  int r = blockIdx.y;
  unsigned short* AB2 = ABall + (long)r * MPAD * 128;
  const int* ssrc = ssrc6 + (long)r * EE;
  int l = threadIdx.x & 63;
  int n = blockIdx.x * 4 + (threadIdx.x >> 6);
  if (n >= NN) return;
  float acc = 0.f;
  int st = off6[(long)r * NN + n], cnt = deg6[(long)r * NN + n];
  int i = 0;
  for (; i + 4 <= cnt; i += 4) {
    int s0 = ssrc[st + i], s1 = ssrc[st + i + 1], s2 = ssrc[st + i + 2], s3 = ssrc[st + i + 3];
    acc += b2f(AB2[(long)s0 * 128 + OO + l]) + b2f(AB2[(long)s1 * 128 + OO + l]) +
           b2f(AB2[(long)s2 * 128 + OO + l]) + b2f(AB2[(long)s3 * 128 + OO + l]);
  }
  for (; i < cnt; i++) {
    int s = ssrc[st + i];
    acc += b2f(AB2[(long)s * 128 + OO + l]);
  }
  AB2[(long)n * 128 + l] = f2b(acc);
}

extern "C" void kernel_launch(void* const* d_in, const int* in_sizes, int n_in,
                              void* d_out, int out_size, void* d_ws, size_t ws_size,
                              hipStream_t stream) {
  (void)in_sizes; (void)n_in; (void)out_size;
  const float* x      = (const float*)d_in[0];
  const int*   ei     = (const int*)d_in[1];
  const float* Wl     = (const float*)d_in[2];
  const float* Wr     = (const float*)d_in[3];
  const float* att    = (const float*)d_in[4];
  const float* bg     = (const float*)d_in[5];
  const float* Wrel1  = (const float*)d_in[6];
  const float* Wroot1 = (const float*)d_in[7];
  const float* b1     = (const float*)d_in[8];
  const float* Wrel2  = (const float*)d_in[9];
  const float* Wroot2 = (const float*)d_in[10];
  const float* b2     = (const float*)d_in[11];
  float* out = (float*)d_out;

  char* ws = (char*)d_ws;
  size_t ofs = 0;
  auto alloc = [&](size_t bytes) {
    char* p = ws + ofs;
    ofs += (bytes + 255) & ~(size_t)255;
    return p;
  };
  unsigned short* Xb   = (unsigned short*)alloc((size_t)MPAD * DD * 2);
  unsigned short* Wt   = (unsigned short*)alloc((size_t)RREL * 512 * DD * 2);
  unsigned short* Wt1  = (unsigned short*)alloc((size_t)RREL * 64 * 512 * 2);
  unsigned short* Wt2  = (unsigned short*)alloc((size_t)RREL * 64 * 128 * 2);
  unsigned short* Yall = (unsigned short*)alloc((size_t)RREL * MPAD * 512 * 2);  // 308 MB
  unsigned short* AB2  = (unsigned short*)alloc((size_t)RREL * MPAD * 128 * 2);  // 77 MB
  int* deg6   = (int*)alloc((size_t)RREL * NN * 4);
  int* off6   = (int*)alloc((size_t)RREL * NN * 4);
  int* cur6   = (int*)alloc((size_t)RREL * NN * 4);
  int* bsum   = (int*)alloc((size_t)RREL * SCAN_B * 4);
  int* ssrc6  = (int*)alloc((size_t)RREL * EE * 4);
  if (ofs > ws_size) return;

  k_cvt_x<<<(int)((long)MPAD * DD / 8 / 256), 256, 0, stream>>>(x, Xb);
  k_repack_w<<<dim3(DD / 32, 512 / 32, RREL), 256, 0, stream>>>(Wl, Wr, Wt);
  k_repack_gc<<<(RREL * 64 * 512 + 255) / 256, 256, 0, stream>>>(Wrel1, Wroot1, Wt1, 512);
  k_repack_gc<<<(RREL * 64 * 128 + 255) / 256, 256, 0, stream>>>(Wrel2, Wroot2, Wt2, 128);
  hipMemsetAsync(deg6, 0, (size_t)RREL * NN * 4, stream);
  k_deg6<<<((long)RREL * EE + 255) / 256, 256, 0, stream>>>(ei, deg6);
  k_bsum<<<dim3(SCAN_B, RREL), 256, 0, stream>>>(deg6, bsum);
  k_bscan<<<1, 384, 0, stream>>>(bsum);
  k_boff<<<dim3(SCAN_B, RREL), 256, 0, stream>>>(deg6, bsum, off6, cur6);
  k_scatter6<<<((long)RREL * EE + 255) / 256, 256, 0, stream>>>(ei, cur6, ssrc6);

  // one fused 8-phase GEMM: all relations, all 3072 output columns
  k_gemm<<<dim3(196 * 12), 512, 0, stream>>>((const short*)Xb, (const short*)Wt, Yall);
  // batched edge + gc stages (blockIdx.y = relation)
  k_gat<<<dim3(NN / 4, RREL), 256, 0, stream>>>(Yall, ssrc6, off6, deg6, att, bg);
  k_agg1<<<dim3(NN / 4, RREL), 256, 0, stream>>>(Yall, ssrc6, off6, deg6);
  k_gcgemm<512, true, true><<<dim3(MPAD / 128, RREL), 256, 0, stream>>>(
      (const short*)Yall, (const short*)Wt1, b1, (void*)AB2, 128, OO, (long)MPAD * 128);
  k_agg2<<<dim3(NN / 4, RREL), 256, 0, stream>>>(AB2, ssrc6, off6, deg6);
  k_gcgemm<128, false, false><<<dim3(MPAD / 128, RREL), 256, 0, stream>>>(
      (const short*)AB2, (const short*)Wt2, b2, (void*)out, RREL * OO, 0, 64);
}

// Round 3
// 1209.920 us; speedup vs baseline: 1.0631x; 1.0133x over previous
//
#include <hip/hip_runtime.h>
#include <hip/hip_bf16.h>
#include <math.h>

#define RREL 6
#define NN   50000
#define EE   200000
#define DD   768
#define HH   4
#define CC   64
#define HC   256
#define OO   64
#define MPAD 50176    // 196 * 256
#define SCAN_B 49     // ceil(NN/1024)
#define NT   12       // 768 / 64 K-tiles

typedef __attribute__((ext_vector_type(8))) short short8;
typedef __attribute__((ext_vector_type(4))) float f32x4;
typedef __attribute__((ext_vector_type(8))) unsigned short ushort8v;
typedef __attribute__((ext_vector_type(4))) unsigned short ushort4v;

__device__ __forceinline__ float b2f(unsigned short u) {
  return __uint_as_float(((unsigned)u) << 16);
}
__device__ __forceinline__ unsigned short f2b(float f) {
  __hip_bfloat16 h = __float2bfloat16(f);
  unsigned short u;
  __builtin_memcpy(&u, &h, 2);
  return u;
}

// global_load_lds, 16B/lane, wave-uniform LDS base + lane*16
__device__ __forceinline__ void gload16(const void* g, void* s) {
  typedef __attribute__((address_space(1))) void gvoid;
  typedef __attribute__((address_space(3))) void svoid;
  __builtin_amdgcn_global_load_lds((gvoid*)(unsigned long long)g,
                                   (svoid*)(unsigned long long)s, 16, 0, 0);
}

// ---------- x -> bf16 (8 elems/thread) ----------
__global__ __launch_bounds__(256) void k_cvt_x(const float* __restrict__ x,
                                               unsigned short* __restrict__ xb) {
  long t = (long)blockIdx.x * 256 + threadIdx.x;
  long base = t * 8;
  int row = (int)(base / DD);
  ushort8v o;
  if (row < NN) {
    float4 a = *(const float4*)(x + base);
    float4 b = *(const float4*)(x + base + 4);
    o[0] = f2b(a.x); o[1] = f2b(a.y); o[2] = f2b(a.z); o[3] = f2b(a.w);
    o[4] = f2b(b.x); o[5] = f2b(b.y); o[6] = f2b(b.z); o[7] = f2b(b.w);
  } else {
    o = (ushort8v)0;
  }
  *(ushort8v*)(xb + base) = o;
}

// ---------- LDS-tiled transpose: Wl|Wr [768][256] -> Wt[r*512+j][768] bf16 ----------
__global__ __launch_bounds__(256) void k_repack_w(const float* __restrict__ Wl,
                                                  const float* __restrict__ Wr,
                                                  unsigned short* __restrict__ Wt) {
  __shared__ float t[32][33];
  int k0 = blockIdx.x * 32, j0 = blockIdx.y * 32, r = blockIdx.z;
  int tx = threadIdx.x & 31, ty = threadIdx.x >> 5;
#pragma unroll
  for (int s = 0; s < 4; s++) {
    int k = k0 + ty + 8 * s, j = j0 + tx;
    float v = (j < HC) ? Wl[((long)r * DD + k) * HC + j]
                       : Wr[((long)r * DD + k) * HC + (j - HC)];
    t[ty + 8 * s][tx] = v;
  }
  __syncthreads();
#pragma unroll
  for (int s = 0; s < 4; s++) {
    int j = j0 + ty + 8 * s, k = k0 + tx;
    Wt[((long)r * 512 + j) * DD + k] = f2b(t[tx][ty + 8 * s]);
  }
}

// ---------- repack [Wrel;Wroot] -> Bt[r][64][K] bf16 ----------
__global__ void k_repack_gc(const float* __restrict__ Wrel, const float* __restrict__ Wroot,
                            unsigned short* __restrict__ Bt, int K) {
  int idx = blockIdx.x * blockDim.x + threadIdx.x;
  if (idx >= RREL * 64 * K) return;
  int k = idx % K;
  int o = (idx / K) % 64;
  int r = idx / (64 * K);
  int h = K >> 1;
  float v = (k < h) ? Wrel[((long)r * h + k) * 64 + o]
                    : Wroot[((long)r * h + (k - h)) * 64 + o];
  Bt[idx] = f2b(v);
}

// ---------- fused 256x256 GEMM, 2-phase/tile: Yall[r][MPAD][512] = Xb @ Wt_all^T ------
// vs previous round: B fragments held in regs for the whole tile (reads 32->24/tile),
// barriers 8->3/tile, pa1 reads issued under MM(0,1)'s MFMA cluster.  Counted-vmcnt
// tile handoff and the LDS XOR swizzle are unchanged.  Epilogue = direct stores
// (round-1 verified; the LDS-staged epilogue regressed and WRITE_SIZE was already ideal).
#define STAGE_A(HALF, TT)                                                              \
  if ((TT) < NT) {                                                                     \
    long ko = (long)(TT) * 128;                                                        \
    char* db = ldsA + (((TT) & 1) << 15);                                              \
    gload16(AgB + (long)((HALF) * 64 + rA) * 1536 + ko + xcol,                         \
            db + ((HALF) * 64) * 128 + wave * 1024);                                   \
    gload16(AgB + (long)((HALF) * 64 + 128 + rA) * 1536 + ko + xcol,                   \
            db + ((HALF) * 64 + 128) * 128 + wave * 1024);                             \
  }

#define STAGE_B(HALF, TT)                                                              \
  if ((TT) < NT) {                                                                     \
    long ko = (long)(TT) * 128;                                                        \
    char* db = ldsB + (((TT) & 1) << 15);                                              \
    gload16(BgB + (long)(rb0 + (HALF) * 32 + lane8) * 1536 + ko + xcol,                \
            db + (rb0 + (HALF) * 32) * 128);                                           \
    gload16(BgB + (long)(rb1 + (HALF) * 32 + lane8) * 1536 + ko + xcol,                \
            db + (rb1 + (HALF) * 32) * 128);                                           \
  }

// one C-quadrant (4x2 fragments) x K=64 using held A-set PA and pb[NH]
#define MMQ(PA, AOFF, NH)                                                              \
  do {                                                                                 \
    _Pragma("unroll") for (int fi = 0; fi < 4; ++fi)                                   \
    _Pragma("unroll") for (int fj = 0; fj < 2; ++fj) {                                 \
      f32x4 c = acc[(AOFF) + fi][(NH) * 2 + fj];                                       \
      c = __builtin_amdgcn_mfma_f32_16x16x32_bf16(PA[fi][0], pb[NH][fj][0], c, 0, 0, 0);\
      c = __builtin_amdgcn_mfma_f32_16x16x32_bf16(PA[fi][1], pb[NH][fj][1], c, 0, 0, 0);\
      acc[(AOFF) + fi][(NH) * 2 + fj] = c;                                             \
    }                                                                                  \
  } while (0)

__global__ __launch_bounds__(512, 2) void k_gemm(const short* __restrict__ A,
                                                 const short* __restrict__ Bt,
                                                 unsigned short* __restrict__ Yall) {
  __shared__ __align__(16) char ldsA[65536];   // 2 bufs x 256 rows x 128 B
  __shared__ __align__(16) char ldsB[65536];
  int tid = threadIdx.x;
  int wgid = blockIdx.x;                       // 2352 = 196*12, 2352 % 8 == 0
  int swz = (wgid & 7) * 294 + (wgid >> 3);    // bijective XCD swizzle
  int bm = swz / 12, bn = swz % 12;            // bn fastest: A panel L2-resident per XCD
  int lane = tid & 63, wave = tid >> 6;
  int warp_m = wave >> 2, warp_n = wave & 3;
  int wm = warp_m * 128, wn = warp_n * 64;
  int l16 = lane & 15, quad = lane >> 4;
  int gm0 = bm * 256;
  const char* AgB = (const char*)A + (long)gm0 * 1536;
  const char* BgB = (const char*)Bt + (long)bn * 256 * 1536;
  int rA = tid >> 3;                           // 0..63: staged row within 64-row issue
  int lane8 = lane >> 3;
  long xcol = (long)(((tid & 7) ^ (rA & 7)) * 16);  // pre-swizzled source col-group
  int rb0 = (wave >> 2) * 64 + (wave & 3) * 8;      // B stage row base (wave-uniform)
  int rb1 = rb0 + 128;
  int s0 = (quad ^ (l16 & 7)) * 16, s1 = s0 ^ 64;   // swizzled ds_read slot bytes
  f32x4 acc[8][4] = {};

  // prologue: tile0 fully + tile1 X halves; wait leaves 2 half-tiles (4 loads) in flight
  STAGE_A(0, 0); STAGE_B(0, 0); STAGE_A(1, 0); STAGE_B(1, 0);
  STAGE_A(0, 1); STAGE_B(0, 1);
  asm volatile("s_waitcnt vmcnt(4)" ::: "memory");
  __builtin_amdgcn_s_barrier();

  for (int t = 0; t < NT; ++t) {
    int bo = (t & 1) << 15;
    const char* Ard = ldsA + bo + (wm + l16) * 128;
    const char* Brd = ldsB + bo + (wn + l16) * 128;
    short8 pa0[4][2], pa1[4][2], pb[2][2][2];
    // ---- phase A: stage Y halves of t+1; read pa0 + ALL pb; 2 MFMA quadrants ----
    STAGE_A(1, t + 1);
    STAGE_B(1, t + 1);
#pragma unroll
    for (int fi = 0; fi < 4; ++fi) {
      pa0[fi][0] = *(const short8*)(Ard + (fi * 16) * 128 + s0);
      pa0[fi][1] = *(const short8*)(Ard + (fi * 16) * 128 + s1);
    }
#pragma unroll
    for (int nh = 0; nh < 2; ++nh)
#pragma unroll
      for (int fj = 0; fj < 2; ++fj) {
        pb[nh][fj][0] = *(const short8*)(Brd + (nh * 32 + fj * 16) * 128 + s0);
        pb[nh][fj][1] = *(const short8*)(Brd + (nh * 32 + fj * 16) * 128 + s1);
      }
    __builtin_amdgcn_s_barrier();
    asm volatile("s_waitcnt lgkmcnt(0)" ::: "memory");
    __builtin_amdgcn_s_setprio(1);
    MMQ(pa0, 0, 0);
    __builtin_amdgcn_s_setprio(0);
    // pa1 reads issue here; their latency hides under MMQ(pa0,0,1)'s 16 MFMA
#pragma unroll
    for (int fi = 0; fi < 4; ++fi) {
      pa1[fi][0] = *(const short8*)(Ard + ((64 + fi * 16)) * 128 + s0);
      pa1[fi][1] = *(const short8*)(Ard + ((64 + fi * 16)) * 128 + s1);
    }
    __builtin_amdgcn_s_setprio(1);
    MMQ(pa0, 0, 1);
    __builtin_amdgcn_s_setprio(0);
    __builtin_amdgcn_s_barrier();
    // ---- phase B: stage X halves of t+2 (freed above); 2 MFMA quadrants ----
    STAGE_A(0, t + 2);
    STAGE_B(0, t + 2);
    asm volatile("s_waitcnt lgkmcnt(0)" ::: "memory");
    __builtin_amdgcn_s_setprio(1);
    MMQ(pa1, 4, 0);
    MMQ(pa1, 4, 1);
    __builtin_amdgcn_s_setprio(0);
    // per-wave counted wait + barrier ==> tile t+1 landed across ALL waves;
    // leaves A-X(t+2), B-X(t+2) (4 loads) in flight across the barrier.
    if (t < NT - 2)       asm volatile("s_waitcnt vmcnt(4)" ::: "memory");
    else if (t == NT - 2) asm volatile("s_waitcnt vmcnt(0)" ::: "memory");
    __builtin_amdgcn_s_barrier();
  }

  int rel = bn >> 1;
  unsigned short* Yr = Yall + (long)rel * MPAD * 512;
  int cb = (bn & 1) * 256 + wn;
#pragma unroll
  for (int i = 0; i < 8; ++i) {
    int rowb = gm0 + wm + (i >> 2) * 64 + (i & 3) * 16 + quad * 4;
#pragma unroll
    for (int j = 0; j < 4; ++j) {
      int col = cb + (j >> 1) * 32 + (j & 1) * 16 + l16;
#pragma unroll
      for (int reg = 0; reg < 4; ++reg)
        Yr[(long)(rowb + reg) * 512 + col] = f2b(acc[i][j][reg]);
    }
  }
}

// ---------- batched small-N MFMA GEMM for GraphConv (blockIdx.y = relation) ----------
template <int K, bool RELU, bool OBF16>
__global__ __launch_bounds__(256) void k_gcgemm(const short* __restrict__ Aall,
                                                const short* __restrict__ Btall,
                                                const float* __restrict__ biasall,
                                                void* __restrict__ outp, long ldo, int ocol,
                                                long orelstride) {
  __shared__ __align__(16) short As[128 * 32];
  __shared__ __align__(16) short Bs[64 * 32];
  int tid = threadIdx.x;
  int bm = blockIdx.x, r = blockIdx.y;
  const short* A  = Aall + (long)r * MPAD * K;
  const short* Bt = Btall + (long)r * 64 * K;
  const float* bias = biasall + (long)r * 64;
  int lane = tid & 63, wave = tid >> 6;
  int quad = lane >> 4, l16 = lane & 15;
  f32x4 acc[2][4] = {};
  const short* Ag = A + (long)bm * 128 * K;
  int lr = lane >> 2, lc = (lane & 3) * 8;
  const short* ga0 = Ag + (long)(wave * 16 + lr) * K + lc;
  const short* ga1 = Ag + (long)(64 + wave * 16 + lr) * K + lc;
  const short* gb0 = Bt + (long)(wave * 16 + lr) * K + lc;
  short* la0 = &As[(wave * 16) * 32];
  short* la1 = &As[(64 + wave * 16) * 32];
  short* lb0 = &Bs[(wave * 16) * 32];
  for (int k0 = 0; k0 < K; k0 += 32) {
    gload16(ga0 + k0, la0);
    gload16(ga1 + k0, la1);
    gload16(gb0 + k0, lb0);
    __syncthreads();
    short8 af[2], bf[4];
#pragma unroll
    for (int i = 0; i < 2; i++) af[i] = *(const short8*)&As[(wave * 32 + i * 16 + l16) * 32 + quad * 8];
#pragma unroll
    for (int j = 0; j < 4; j++) bf[j] = *(const short8*)&Bs[(j * 16 + l16) * 32 + quad * 8];
#pragma unroll
    for (int i = 0; i < 2; i++)
#pragma unroll
      for (int j = 0; j < 4; j++)
        acc[i][j] = __builtin_amdgcn_mfma_f32_16x16x32_bf16(af[i], bf[j], acc[i][j], 0, 0, 0);
    __syncthreads();
  }
#pragma unroll
  for (int i = 0; i < 2; i++)
#pragma unroll
    for (int j = 0; j < 4; j++)
#pragma unroll
      for (int reg = 0; reg < 4; reg++) {
        int row = bm * 128 + wave * 32 + i * 16 + quad * 4 + reg;
        int col = j * 16 + l16;
        float v = acc[i][j][reg] + bias[col];
        if (RELU) v = fmaxf(v, 0.f);
        if (OBF16) {
          ((unsigned short*)outp)[(long)r * orelstride + (long)row * ldo + ocol + col] = f2b(v);
        } else {
          if (row < NN) ((float*)outp)[(long)r * orelstride + (long)row * ldo + ocol + col] = v;
        }
      }
}

// ---------- batched CSR build ----------
__global__ void k_deg6(const int* __restrict__ ei, int* __restrict__ deg6) {
  long e = (long)blockIdx.x * blockDim.x + threadIdx.x;
  if (e >= (long)RREL * EE) return;
  int r = e / EE, i = e % EE;
  int t = ei[(long)r * 2 * EE + EE + i];
  atomicAdd(&deg6[(long)r * NN + t], 1);
}

__global__ __launch_bounds__(256) void k_bsum(const int* __restrict__ deg6, int* __restrict__ bsum) {
  int r = blockIdx.y, b = blockIdx.x, tid = threadIdx.x;
  const int* deg = deg6 + (long)r * NN;
  int i0 = b * 1024 + tid * 4;
  int s = 0;
#pragma unroll
  for (int j = 0; j < 4; j++) { int i = i0 + j; if (i < NN) s += deg[i]; }
#pragma unroll
  for (int m = 1; m < 64; m <<= 1) s += __shfl_xor(s, m);
  __shared__ int ws[4];
  if ((tid & 63) == 0) ws[tid >> 6] = s;
  __syncthreads();
  if (tid == 0) bsum[r * SCAN_B + b] = ws[0] + ws[1] + ws[2] + ws[3];
}

__global__ void k_bscan(int* __restrict__ bsum) {   // 1 block, 384 thr = 6 waves
  int w = threadIdx.x >> 6, l = threadIdx.x & 63;
  int v = (l < SCAN_B) ? bsum[w * SCAN_B + l] : 0;
  int incl = v;
#pragma unroll
  for (int d = 1; d < 64; d <<= 1) { int t = __shfl_up(incl, d); if (l >= d) incl += t; }
  if (l < SCAN_B) bsum[w * SCAN_B + l] = incl - v;   // exclusive
}

__global__ __launch_bounds__(256) void k_boff(const int* __restrict__ deg6, const int* __restrict__ bsum,
                                              int* __restrict__ off6, int* __restrict__ cur6) {
  int r = blockIdx.y, b = blockIdx.x, tid = threadIdx.x;
  const int* deg = deg6 + (long)r * NN;
  int i0 = b * 1024 + tid * 4;
  int v[4], s = 0;
#pragma unroll
  for (int j = 0; j < 4; j++) { int i = i0 + j; v[j] = (i < NN) ? deg[i] : 0; s += v[j]; }
  int l = tid & 63, wv = tid >> 6;
  int incl = s;
#pragma unroll
  for (int d = 1; d < 64; d <<= 1) { int t = __shfl_up(incl, d); if (l >= d) incl += t; }
  __shared__ int ws[4];
  if (l == 63) ws[wv] = incl;
  __syncthreads();
  int pre = incl - s;
  for (int k = 0; k < wv; k++) pre += ws[k];
  pre += bsum[r * SCAN_B + b];
  int e0 = pre;
#pragma unroll
  for (int j = 0; j < 4; j++) {
    int i = i0 + j;
    if (i < NN) { off6[(long)r * NN + i] = e0; cur6[(long)r * NN + i] = e0; }
    e0 += v[j];
  }
}

__global__ void k_scatter6(const int* __restrict__ ei, int* __restrict__ cur6,
                           int* __restrict__ ssrc6) {
  long e = (long)blockIdx.x * blockDim.x + threadIdx.x;
  if (e >= (long)RREL * EE) return;
  int r = e / EE, i = e % EE;
  int src = ei[(long)r * 2 * EE + i];
  int t   = ei[(long)r * 2 * EE + EE + i];
  int p = atomicAdd(&cur6[(long)r * NN + t], 1);
  ssrc6[(long)r * EE + p] = src;
}

// ---------- batched fused GATv2 (blockIdx.y = r); h1 overwrites Y[:,256:512] ----------
__global__ __launch_bounds__(256) void k_gat(unsigned short* __restrict__ Yall,
                                             const int* __restrict__ ssrc6,
                                             const int* __restrict__ off6, const int* __restrict__ deg6,
                                             const float* __restrict__ attall,
                                             const float* __restrict__ bgall) {
  int r = blockIdx.y;
  unsigned short* Y = Yall + (long)r * MPAD * 512;
  const int* ssrc = ssrc6 + (long)r * EE;
  const float* att = attall + r * HC;
  const float* bg  = bgall + r * HC;
  int l = threadIdx.x & 63;
  int n = blockIdx.x * 4 + (threadIdx.x >> 6);
  if (n >= NN) return;
  const unsigned short* yb = Y + (long)n * 512;
  ushort4v xlv = *(const ushort4v*)(yb + 4 * l);
  ushort4v xrv = *(const ushort4v*)(yb + 256 + 4 * l);
  float xl[4], xr[4];
#pragma unroll
  for (int j = 0; j < 4; j++) { xl[j] = b2f(xlv[j]); xr[j] = b2f(xrv[j]); }
  float4 at4 = *(const float4*)(att + 4 * l);
  float at[4] = {at4.x, at4.y, at4.z, at4.w};
  float num[4] = {0.f, 0.f, 0.f, 0.f}, den = 0.f;
  // self loop
  {
    float lg = 0.f;
#pragma unroll
    for (int j = 0; j < 4; j++) {
      float e = xl[j] + xr[j];
      e = e > 0.f ? e : 0.2f * e;
      lg += at[j] * e;
    }
    lg += __shfl_xor(lg, 1); lg += __shfl_xor(lg, 2);
    lg += __shfl_xor(lg, 4); lg += __shfl_xor(lg, 8);
    float a = expf(lg);
    den += a;
#pragma unroll
    for (int j = 0; j < 4; j++) num[j] += a * xl[j];
  }
  int st = off6[(long)r * NN + n], cnt = deg6[(long)r * NN + n];
  int i = 0;
  for (; i + 2 <= cnt; i += 2) {   // 2-way unroll: two gathers in flight
    int s0 = ssrc[st + i], s1 = ssrc[st + i + 1];
    ushort4v v0 = *(const ushort4v*)(Y + (long)s0 * 512 + 4 * l);
    ushort4v v1 = *(const ushort4v*)(Y + (long)s1 * 512 + 4 * l);
    float x0[4], x1[4];
#pragma unroll
    for (int j = 0; j < 4; j++) { x0[j] = b2f(v0[j]); x1[j] = b2f(v1[j]); }
    float lg0 = 0.f, lg1 = 0.f;
#pragma unroll
    for (int j = 0; j < 4; j++) {
      float e0 = x0[j] + xr[j]; e0 = e0 > 0.f ? e0 : 0.2f * e0; lg0 += at[j] * e0;
      float e1 = x1[j] + xr[j]; e1 = e1 > 0.f ? e1 : 0.2f * e1; lg1 += at[j] * e1;
    }
    lg0 += __shfl_xor(lg0, 1); lg1 += __shfl_xor(lg1, 1);
    lg0 += __shfl_xor(lg0, 2); lg1 += __shfl_xor(lg1, 2);
    lg0 += __shfl_xor(lg0, 4); lg1 += __shfl_xor(lg1, 4);
    lg0 += __shfl_xor(lg0, 8); lg1 += __shfl_xor(lg1, 8);
    float a0 = expf(lg0), a1 = expf(lg1);
    den += a0 + a1;
#pragma unroll
    for (int j = 0; j < 4; j++) num[j] += a0 * x0[j] + a1 * x1[j];
  }
  if (i < cnt) {
    int s0 = ssrc[st + i];
    ushort4v v0 = *(const ushort4v*)(Y + (long)s0 * 512 + 4 * l);
    float x0[4];
#pragma unroll
    for (int j = 0; j < 4; j++) x0[j] = b2f(v0[j]);
    float lg = 0.f;
#pragma unroll
    for (int j = 0; j < 4; j++) {
      float e = x0[j] + xr[j];
      e = e > 0.f ? e : 0.2f * e;
      lg += at[j] * e;
    }
    lg += __shfl_xor(lg, 1); lg += __shfl_xor(lg, 2);
    lg += __shfl_xor(lg, 4); lg += __shfl_xor(lg, 8);
    float a = expf(lg);
    den += a;
#pragma unroll
    for (int j = 0; j < 4; j++) num[j] += a * x0[j];
  }
  float4 bg4 = *(const float4*)(bg + 4 * l);
  float bgj[4] = {bg4.x, bg4.y, bg4.z, bg4.w};
  ushort4v o;
  float inv = 1.f / (den + 1e-16f);
#pragma unroll
  for (int j = 0; j < 4; j++) o[j] = f2b(fmaxf(num[j] * inv + bgj[j], 0.f));
  *(ushort4v*)(Y + (long)n * 512 + 256 + 4 * l) = o;   // h1 over dead xr
}

// ---------- batched CSR gather-sum of h1; agg over dead xl half ----------
__global__ __launch_bounds__(256) void k_agg1(unsigned short* __restrict__ Yall,
                                              const int* __restrict__ ssrc6,
                                              const int* __restrict__ off6,
                                              const int* __restrict__ deg6) {
  int r = blockIdx.y;
  unsigned short* Y = Yall + (long)r * MPAD * 512;
  const int* ssrc = ssrc6 + (long)r * EE;
  int l = threadIdx.x & 63;
  int n = blockIdx.x * 4 + (threadIdx.x >> 6);
  if (n >= NN) return;
  float acc[4] = {0.f, 0.f, 0.f, 0.f};
  int st = off6[(long)r * NN + n], cnt = deg6[(long)r * NN + n];
  int i = 0;
  for (; i + 4 <= cnt; i += 4) {
    int s0 = ssrc[st + i], s1 = ssrc[st + i + 1], s2 = ssrc[st + i + 2], s3 = ssrc[st + i + 3];
    ushort4v v0 = *(const ushort4v*)(Y + (long)s0 * 512 + 256 + 4 * l);
    ushort4v v1 = *(const ushort4v*)(Y + (long)s1 * 512 + 256 + 4 * l);
    ushort4v v2 = *(const ushort4v*)(Y + (long)s2 * 512 + 256 + 4 * l);
    ushort4v v3 = *(const ushort4v*)(Y + (long)s3 * 512 + 256 + 4 * l);
#pragma unroll
    for (int j = 0; j < 4; j++)
      acc[j] += b2f(v0[j]) + b2f(v1[j]) + b2f(v2[j]) + b2f(v3[j]);
  }
  for (; i < cnt; i++) {
    int s = ssrc[st + i];
    ushort4v v = *(const ushort4v*)(Y + (long)s * 512 + 256 + 4 * l);
#pragma unroll
    for (int j = 0; j < 4; j++) acc[j] += b2f(v[j]);
  }
  ushort4v o;
#pragma unroll
  for (int j = 0; j < 4; j++) o[j] = f2b(acc[j]);
  *(ushort4v*)(Y + (long)n * 512 + 4 * l) = o;
}

// ---------- batched CSR gather-sum of h2 ----------
__global__ __launch_bounds__(256) void k_agg2(unsigned short* __restrict__ ABall,
                                              const int* __restrict__ ssrc6,
                                              const int* __restrict__ off6,
                                              const int* __restrict__ deg6) {
  int r = blockIdx.y;
  unsigned short* AB2 = ABall + (long)r * MPAD * 128;
  const int* ssrc = ssrc6 + (long)r * EE;
  int l = threadIdx.x & 63;
  int n = blockIdx.x * 4 + (threadIdx.x >> 6);
  if (n >= NN) return;
  float acc = 0.f;
  int st = off6[(long)r * NN + n], cnt = deg6[(long)r * NN + n];
  int i = 0;
  for (; i + 4 <= cnt; i += 4) {
    int s0 = ssrc[st + i], s1 = ssrc[st + i + 1], s2 = ssrc[st + i + 2], s3 = ssrc[st + i + 3];
    acc += b2f(AB2[(long)s0 * 128 + OO + l]) + b2f(AB2[(long)s1 * 128 + OO + l]) +
           b2f(AB2[(long)s2 * 128 + OO + l]) + b2f(AB2[(long)s3 * 128 + OO + l]);
  }
  for (; i < cnt; i++) {
    int s = ssrc[st + i];
    acc += b2f(AB2[(long)s * 128 + OO + l]);
  }
  AB2[(long)n * 128 + l] = f2b(acc);
}

extern "C" void kernel_launch(void* const* d_in, const int* in_sizes, int n_in,
                              void* d_out, int out_size, void* d_ws, size_t ws_size,
                              hipStream_t stream) {
  (void)in_sizes; (void)n_in; (void)out_size;
  const float* x      = (const float*)d_in[0];
  const int*   ei     = (const int*)d_in[1];
  const float* Wl     = (const float*)d_in[2];
  const float* Wr     = (const float*)d_in[3];
  const float* att    = (const float*)d_in[4];
  const float* bg     = (const float*)d_in[5];
  const float* Wrel1  = (const float*)d_in[6];
  const float* Wroot1 = (const float*)d_in[7];
  const float* b1     = (const float*)d_in[8];
  const float* Wrel2  = (const float*)d_in[9];
  const float* Wroot2 = (const float*)d_in[10];
  const float* b2     = (const float*)d_in[11];
  float* out = (float*)d_out;

  char* ws = (char*)d_ws;
  size_t ofs = 0;
  auto alloc = [&](size_t bytes) {
    char* p = ws + ofs;
    ofs += (bytes + 255) & ~(size_t)255;
    return p;
  };
  unsigned short* Xb   = (unsigned short*)alloc((size_t)MPAD * DD * 2);
  unsigned short* Wt   = (unsigned short*)alloc((size_t)RREL * 512 * DD * 2);
  unsigned short* Wt1  = (unsigned short*)alloc((size_t)RREL * 64 * 512 * 2);
  unsigned short* Wt2  = (unsigned short*)alloc((size_t)RREL * 64 * 128 * 2);
  unsigned short* Yall = (unsigned short*)alloc((size_t)RREL * MPAD * 512 * 2);  // 308 MB
  unsigned short* AB2  = (unsigned short*)alloc((size_t)RREL * MPAD * 128 * 2);  // 77 MB
  int* deg6   = (int*)alloc((size_t)RREL * NN * 4);
  int* off6   = (int*)alloc((size_t)RREL * NN * 4);
  int* cur6   = (int*)alloc((size_t)RREL * NN * 4);
  int* bsum   = (int*)alloc((size_t)RREL * SCAN_B * 4);
  int* ssrc6  = (int*)alloc((size_t)RREL * EE * 4);
  if (ofs > ws_size) return;

  k_cvt_x<<<(int)((long)MPAD * DD / 8 / 256), 256, 0, stream>>>(x, Xb);
  k_repack_w<<<dim3(DD / 32, 512 / 32, RREL), 256, 0, stream>>>(Wl, Wr, Wt);
  k_repack_gc<<<(RREL * 64 * 512 + 255) / 256, 256, 0, stream>>>(Wrel1, Wroot1, Wt1, 512);
  k_repack_gc<<<(RREL * 64 * 128 + 255) / 256, 256, 0, stream>>>(Wrel2, Wroot2, Wt2, 128);
  hipMemsetAsync(deg6, 0, (size_t)RREL * NN * 4, stream);
  k_deg6<<<((long)RREL * EE + 255) / 256, 256, 0, stream>>>(ei, deg6);
  k_bsum<<<dim3(SCAN_B, RREL), 256, 0, stream>>>(deg6, bsum);
  k_bscan<<<1, 384, 0, stream>>>(bsum);
  k_boff<<<dim3(SCAN_B, RREL), 256, 0, stream>>>(deg6, bsum, off6, cur6);
  k_scatter6<<<((long)RREL * EE + 255) / 256, 256, 0, stream>>>(ei, cur6, ssrc6);

  // one fused 2-phase GEMM: all relations, all 3072 output columns
  k_gemm<<<dim3(196 * 12), 512, 0, stream>>>((const short*)Xb, (const short*)Wt, Yall);
  // batched edge + gc stages (blockIdx.y = relation)
  k_gat<<<dim3(NN / 4, RREL), 256, 0, stream>>>(Yall, ssrc6, off6, deg6, att, bg);
  k_agg1<<<dim3(NN / 4, RREL), 256, 0, stream>>>(Yall, ssrc6, off6, deg6);
  k_gcgemm<512, true, true><<<dim3(MPAD / 128, RREL), 256, 0, stream>>>(
      (const short*)Yall, (const short*)Wt1, b1, (void*)AB2, 128, OO, (long)MPAD * 128);
  k_agg2<<<dim3(NN / 4, RREL), 256, 0, stream>>>(AB2, ssrc6, off6, deg6);
  k_gcgemm<128, false, false><<<dim3(MPAD / 128, RREL), 256, 0, stream>>>(
      (const short*)AB2, (const short*)Wt2, b2, (void*)out, RREL * OO, 0, 64);
}

// Round 5
// 1142.035 us; speedup vs baseline: 1.1263x; 1.0594x over previous
//
#include <hip/hip_runtime.h>
#include <hip/hip_bf16.h>
#include <math.h>

#define RREL 6
#define NN   50000
#define EE   200000
#define DD   768
#define HH   4
#define CC   64
#define HC   256
#define OO   64
#define MPAD 50176    // 196 * 256
#define SCAN_B 49     // ceil(NN/1024)
#define NT   12       // 768 / 64 K-tiles

typedef __attribute__((ext_vector_type(8))) short short8;
typedef __attribute__((ext_vector_type(4))) float f32x4;
typedef __attribute__((ext_vector_type(8))) unsigned short ushort8v;
typedef __attribute__((ext_vector_type(4))) unsigned short ushort4v;

__device__ __forceinline__ float b2f(unsigned short u) {
  return __uint_as_float(((unsigned)u) << 16);
}
__device__ __forceinline__ unsigned short f2b(float f) {
  __hip_bfloat16 h = __float2bfloat16(f);
  unsigned short u;
  __builtin_memcpy(&u, &h, 2);
  return u;
}

// global_load_lds, 16B/lane, wave-uniform LDS base + lane*16
__device__ __forceinline__ void gload16(const void* g, void* s) {
  typedef __attribute__((address_space(1))) void gvoid;
  typedef __attribute__((address_space(3))) void svoid;
  __builtin_amdgcn_global_load_lds((gvoid*)(unsigned long long)g,
                                   (svoid*)(unsigned long long)s, 16, 0, 0);
}

// ---------- x -> bf16 (8 elems/thread) ----------
__global__ __launch_bounds__(256) void k_cvt_x(const float* __restrict__ x,
                                               unsigned short* __restrict__ xb) {
  long t = (long)blockIdx.x * 256 + threadIdx.x;
  long base = t * 8;
  int row = (int)(base / DD);
  ushort8v o;
  if (row < NN) {
    float4 a = *(const float4*)(x + base);
    float4 b = *(const float4*)(x + base + 4);
    o[0] = f2b(a.x); o[1] = f2b(a.y); o[2] = f2b(a.z); o[3] = f2b(a.w);
    o[4] = f2b(b.x); o[5] = f2b(b.y); o[6] = f2b(b.z); o[7] = f2b(b.w);
  } else {
    o = (ushort8v)0;
  }
  *(ushort8v*)(xb + base) = o;
}

// ---------- LDS-tiled transpose: Wl|Wr [768][256] -> Wt[r*512+j][768] bf16 ----------
__global__ __launch_bounds__(256) void k_repack_w(const float* __restrict__ Wl,
                                                  const float* __restrict__ Wr,
                                                  unsigned short* __restrict__ Wt) {
  __shared__ float t[32][33];
  int k0 = blockIdx.x * 32, j0 = blockIdx.y * 32, r = blockIdx.z;
  int tx = threadIdx.x & 31, ty = threadIdx.x >> 5;
#pragma unroll
  for (int s = 0; s < 4; s++) {
    int k = k0 + ty + 8 * s, j = j0 + tx;
    float v = (j < HC) ? Wl[((long)r * DD + k) * HC + j]
                       : Wr[((long)r * DD + k) * HC + (j - HC)];
    t[ty + 8 * s][tx] = v;
  }
  __syncthreads();
#pragma unroll
  for (int s = 0; s < 4; s++) {
    int j = j0 + ty + 8 * s, k = k0 + tx;
    Wt[((long)r * 512 + j) * DD + k] = f2b(t[tx][ty + 8 * s]);
  }
}

// ---------- repack [Wrel;Wroot] -> Bt[r][128][K] bf16 (cols 0-63 = rel, 64-127 = root) -
__global__ void k_repack_zr(const float* __restrict__ Wrel, const float* __restrict__ Wroot,
                            unsigned short* __restrict__ Bt, int K) {
  int idx = blockIdx.x * blockDim.x + threadIdx.x;
  if (idx >= RREL * 128 * K) return;
  int k = idx % K;
  int j = (idx / K) % 128;
  int r = idx / (128 * K);
  float v = (j < 64) ? Wrel[((long)r * K + k) * 64 + j]
                     : Wroot[((long)r * K + k) * 64 + (j - 64)];
  Bt[idx] = f2b(v);
}

// ---------- fused 256x256 GEMM, 2-phase/tile: Yall[r][MPAD][512] = Xb @ Wt_all^T ------
#define STAGE_A(HALF, TT)                                                              \
  if ((TT) < NT) {                                                                     \
    long ko = (long)(TT) * 128;                                                        \
    char* db = ldsA + (((TT) & 1) << 15);                                              \
    gload16(AgB + (long)((HALF) * 64 + rA) * 1536 + ko + xcol,                         \
            db + ((HALF) * 64) * 128 + wave * 1024);                                   \
    gload16(AgB + (long)((HALF) * 64 + 128 + rA) * 1536 + ko + xcol,                   \
            db + ((HALF) * 64 + 128) * 128 + wave * 1024);                             \
  }

#define STAGE_B(HALF, TT)                                                              \
  if ((TT) < NT) {                                                                     \
    long ko = (long)(TT) * 128;                                                        \
    char* db = ldsB + (((TT) & 1) << 15);                                              \
    gload16(BgB + (long)(rb0 + (HALF) * 32 + lane8) * 1536 + ko + xcol,                \
            db + (rb0 + (HALF) * 32) * 128);                                           \
    gload16(BgB + (long)(rb1 + (HALF) * 32 + lane8) * 1536 + ko + xcol,                \
            db + (rb1 + (HALF) * 32) * 128);                                           \
  }

// one C-quadrant (4x2 fragments) x K=64 using held A-set PA and pb[NH]
#define MMQ(PA, AOFF, NH)                                                              \
  do {                                                                                 \
    _Pragma("unroll") for (int fi = 0; fi < 4; ++fi)                                   \
    _Pragma("unroll") for (int fj = 0; fj < 2; ++fj) {                                 \
      f32x4 c = acc[(AOFF) + fi][(NH) * 2 + fj];                                       \
      c = __builtin_amdgcn_mfma_f32_16x16x32_bf16(PA[fi][0], pb[NH][fj][0], c, 0, 0, 0);\
      c = __builtin_amdgcn_mfma_f32_16x16x32_bf16(PA[fi][1], pb[NH][fj][1], c, 0, 0, 0);\
      acc[(AOFF) + fi][(NH) * 2 + fj] = c;                                             \
    }                                                                                  \
  } while (0)

__global__ __launch_bounds__(512, 2) void k_gemm(const short* __restrict__ A,
                                                 const short* __restrict__ Bt,
                                                 unsigned short* __restrict__ Yall) {
  __shared__ __align__(16) char ldsA[65536];   // 2 bufs x 256 rows x 128 B
  __shared__ __align__(16) char ldsB[65536];
  int tid = threadIdx.x;
  int wgid = blockIdx.x;                       // 2352 = 196*12, 2352 % 8 == 0
  int swz = (wgid & 7) * 294 + (wgid >> 3);    // bijective XCD swizzle
  int bm = swz / 12, bn = swz % 12;            // bn fastest: A panel L2-resident per XCD
  int lane = tid & 63, wave = tid >> 6;
  int warp_m = wave >> 2, warp_n = wave & 3;
  int wm = warp_m * 128, wn = warp_n * 64;
  int l16 = lane & 15, quad = lane >> 4;
  int gm0 = bm * 256;
  const char* AgB = (const char*)A + (long)gm0 * 1536;
  const char* BgB = (const char*)Bt + (long)bn * 256 * 1536;
  int rA = tid >> 3;                           // 0..63: staged row within 64-row issue
  int lane8 = lane >> 3;
  long xcol = (long)(((tid & 7) ^ (rA & 7)) * 16);  // pre-swizzled source col-group
  int rb0 = (wave >> 2) * 64 + (wave & 3) * 8;      // B stage row base (wave-uniform)
  int rb1 = rb0 + 128;
  int s0 = (quad ^ (l16 & 7)) * 16, s1 = s0 ^ 64;   // swizzled ds_read slot bytes
  f32x4 acc[8][4] = {};

  // prologue: tile0 fully + tile1 X halves; wait leaves 2 half-tiles (4 loads) in flight
  STAGE_A(0, 0); STAGE_B(0, 0); STAGE_A(1, 0); STAGE_B(1, 0);
  STAGE_A(0, 1); STAGE_B(0, 1);
  asm volatile("s_waitcnt vmcnt(4)" ::: "memory");
  __builtin_amdgcn_s_barrier();

  for (int t = 0; t < NT; ++t) {
    int bo = (t & 1) << 15;
    const char* Ard = ldsA + bo + (wm + l16) * 128;
    const char* Brd = ldsB + bo + (wn + l16) * 128;
    short8 pa0[4][2], pa1[4][2], pb[2][2][2];
    // ---- phase A: stage Y halves of t+1; read pa0 + ALL pb; 2 MFMA quadrants ----
    STAGE_A(1, t + 1);
    STAGE_B(1, t + 1);
#pragma unroll
    for (int fi = 0; fi < 4; ++fi) {
      pa0[fi][0] = *(const short8*)(Ard + (fi * 16) * 128 + s0);
      pa0[fi][1] = *(const short8*)(Ard + (fi * 16) * 128 + s1);
    }
#pragma unroll
    for (int nh = 0; nh < 2; ++nh)
#pragma unroll
      for (int fj = 0; fj < 2; ++fj) {
        pb[nh][fj][0] = *(const short8*)(Brd + (nh * 32 + fj * 16) * 128 + s0);
        pb[nh][fj][1] = *(const short8*)(Brd + (nh * 32 + fj * 16) * 128 + s1);
      }
    __builtin_amdgcn_s_barrier();
    asm volatile("s_waitcnt lgkmcnt(0)" ::: "memory");
    __builtin_amdgcn_s_setprio(1);
    MMQ(pa0, 0, 0);
    __builtin_amdgcn_s_setprio(0);
    // pa1 reads issue here; their latency hides under MMQ(pa0,0,1)'s 16 MFMA
#pragma unroll
    for (int fi = 0; fi < 4; ++fi) {
      pa1[fi][0] = *(const short8*)(Ard + ((64 + fi * 16)) * 128 + s0);
      pa1[fi][1] = *(const short8*)(Ard + ((64 + fi * 16)) * 128 + s1);
    }
    __builtin_amdgcn_s_setprio(1);
    MMQ(pa0, 0, 1);
    __builtin_amdgcn_s_setprio(0);
    __builtin_amdgcn_s_barrier();
    // ---- phase B: stage X halves of t+2 (freed above); 2 MFMA quadrants ----
    STAGE_A(0, t + 2);
    STAGE_B(0, t + 2);
    asm volatile("s_waitcnt lgkmcnt(0)" ::: "memory");
    __builtin_amdgcn_s_setprio(1);
    MMQ(pa1, 4, 0);
    MMQ(pa1, 4, 1);
    __builtin_amdgcn_s_setprio(0);
    if (t < NT - 2)       asm volatile("s_waitcnt vmcnt(4)" ::: "memory");
    else if (t == NT - 2) asm volatile("s_waitcnt vmcnt(0)" ::: "memory");
    __builtin_amdgcn_s_barrier();
  }

  int rel = bn >> 1;
  unsigned short* Yr = Yall + (long)rel * MPAD * 512;
  int cb = (bn & 1) * 256 + wn;
#pragma unroll
  for (int i = 0; i < 8; ++i) {
    int rowb = gm0 + wm + (i >> 2) * 64 + (i & 3) * 16 + quad * 4;
#pragma unroll
    for (int j = 0; j < 4; ++j) {
      int col = cb + (j >> 1) * 32 + (j & 1) * 16 + l16;
#pragma unroll
      for (int reg = 0; reg < 4; ++reg)
        Yr[(long)(rowb + reg) * 512 + col] = f2b(acc[i][j][reg]);
    }
  }
}

// ---------- batched 128-col MFMA GEMM: ZR[r][MPAD][128] = A @ Bt^T (no bias) ----------
// A is rel-strided bf16 with row stride lda and column offset aoff.
template <int K>
__global__ __launch_bounds__(256) void k_zr(const unsigned short* __restrict__ Abase,
                                            long lda, long aoff,
                                            const unsigned short* __restrict__ Btall,
                                            unsigned short* __restrict__ ZRall) {
  __shared__ __align__(16) short As[128 * 32];
  __shared__ __align__(16) short Bs[128 * 32];
  int tid = threadIdx.x;
  int bm = blockIdx.x, r = blockIdx.y;
  const unsigned short* A  = Abase + (long)r * MPAD * lda + aoff;
  const unsigned short* Bt = Btall + (long)r * 128 * K;
  unsigned short* ZR = ZRall + (long)r * MPAD * 128;
  int lane = tid & 63, wave = tid >> 6;
  int quad = lane >> 4, l16 = lane & 15;
  f32x4 acc[2][8] = {};
  const unsigned short* Ag = A + (long)bm * 128 * lda;
  int lr = lane >> 2, lc = (lane & 3) * 8;
  const unsigned short* ga0 = Ag + (long)(wave * 16 + lr) * lda + lc;
  const unsigned short* ga1 = Ag + (long)(64 + wave * 16 + lr) * lda + lc;
  const unsigned short* gb0 = Bt + (long)(wave * 16 + lr) * K + lc;
  const unsigned short* gb1 = Bt + (long)(64 + wave * 16 + lr) * K + lc;
  short* la0 = &As[(wave * 16) * 32];
  short* la1 = &As[(64 + wave * 16) * 32];
  short* lb0 = &Bs[(wave * 16) * 32];
  short* lb1 = &Bs[(64 + wave * 16) * 32];
  for (int k0 = 0; k0 < K; k0 += 32) {
    gload16(ga0 + k0, la0);
    gload16(ga1 + k0, la1);
    gload16(gb0 + k0, lb0);
    gload16(gb1 + k0, lb1);
    __syncthreads();
    short8 af[2], bf[8];
#pragma unroll
    for (int i = 0; i < 2; i++) af[i] = *(const short8*)&As[(wave * 32 + i * 16 + l16) * 32 + quad * 8];
#pragma unroll
    for (int j = 0; j < 8; j++) bf[j] = *(const short8*)&Bs[(j * 16 + l16) * 32 + quad * 8];
#pragma unroll
    for (int i = 0; i < 2; i++)
#pragma unroll
      for (int j = 0; j < 8; j++)
        acc[i][j] = __builtin_amdgcn_mfma_f32_16x16x32_bf16(af[i], bf[j], acc[i][j], 0, 0, 0);
    __syncthreads();
  }
#pragma unroll
  for (int i = 0; i < 2; i++)
#pragma unroll
    for (int j = 0; j < 8; j++)
#pragma unroll
      for (int reg = 0; reg < 4; reg++) {
        int row = bm * 128 + wave * 32 + i * 16 + quad * 4 + reg;
        int col = j * 16 + l16;
        ZR[(long)row * 128 + col] = f2b(acc[i][j][reg]);
      }
}

// ---------- batched CSR build ----------
__global__ void k_deg6(const int* __restrict__ ei, int* __restrict__ deg6) {
  long e = (long)blockIdx.x * blockDim.x + threadIdx.x;
  if (e >= (long)RREL * EE) return;
  int r = e / EE, i = e % EE;
  int t = ei[(long)r * 2 * EE + EE + i];
  atomicAdd(&deg6[(long)r * NN + t], 1);
}

__global__ __launch_bounds__(256) void k_bsum(const int* __restrict__ deg6, int* __restrict__ bsum) {
  int r = blockIdx.y, b = blockIdx.x, tid = threadIdx.x;
  const int* deg = deg6 + (long)r * NN;
  int i0 = b * 1024 + tid * 4;
  int s = 0;
#pragma unroll
  for (int j = 0; j < 4; j++) { int i = i0 + j; if (i < NN) s += deg[i]; }
#pragma unroll
  for (int m = 1; m < 64; m <<= 1) s += __shfl_xor(s, m);
  __shared__ int ws[4];
  if ((tid & 63) == 0) ws[tid >> 6] = s;
  __syncthreads();
  if (tid == 0) bsum[r * SCAN_B + b] = ws[0] + ws[1] + ws[2] + ws[3];
}

__global__ void k_bscan(int* __restrict__ bsum) {   // 1 block, 384 thr = 6 waves
  int w = threadIdx.x >> 6, l = threadIdx.x & 63;
  int v = (l < SCAN_B) ? bsum[w * SCAN_B + l] : 0;
  int incl = v;
#pragma unroll
  for (int d = 1; d < 64; d <<= 1) { int t = __shfl_up(incl, d); if (l >= d) incl += t; }
  if (l < SCAN_B) bsum[w * SCAN_B + l] = incl - v;   // exclusive
}

__global__ __launch_bounds__(256) void k_boff(const int* __restrict__ deg6, const int* __restrict__ bsum,
                                              int* __restrict__ off6, int* __restrict__ cur6) {
  int r = blockIdx.y, b = blockIdx.x, tid = threadIdx.x;
  const int* deg = deg6 + (long)r * NN;
  int i0 = b * 1024 + tid * 4;
  int v[4], s = 0;
#pragma unroll
  for (int j = 0; j < 4; j++) { int i = i0 + j; v[j] = (i < NN) ? deg[i] : 0; s += v[j]; }
  int l = tid & 63, wv = tid >> 6;
  int incl = s;
#pragma unroll
  for (int d = 1; d < 64; d <<= 1) { int t = __shfl_up(incl, d); if (l >= d) incl += t; }
  __shared__ int ws[4];
  if (l == 63) ws[wv] = incl;
  __syncthreads();
  int pre = incl - s;
  for (int k = 0; k < wv; k++) pre += ws[k];
  pre += bsum[r * SCAN_B + b];
  int e0 = pre;
#pragma unroll
  for (int j = 0; j < 4; j++) {
    int i = i0 + j;
    if (i < NN) { off6[(long)r * NN + i] = e0; cur6[(long)r * NN + i] = e0; }
    e0 += v[j];
  }
}

__global__ void k_scatter6(const int* __restrict__ ei, int* __restrict__ cur6,
                           int* __restrict__ ssrc6) {
  long e = (long)blockIdx.x * blockDim.x + threadIdx.x;
  if (e >= (long)RREL * EE) return;
  int r = e / EE, i = e % EE;
  int src = ei[(long)r * 2 * EE + i];
  int t   = ei[(long)r * 2 * EE + EE + i];
  int p = atomicAdd(&cur6[(long)r * NN + t], 1);
  ssrc6[(long)r * EE + p] = src;
}

// ---------- batched fused GATv2 (blockIdx.y = r); h1 overwrites Y[:,256:512] ----------
__global__ __launch_bounds__(256) void k_gat(unsigned short* __restrict__ Yall,
                                             const int* __restrict__ ssrc6,
                                             const int* __restrict__ off6, const int* __restrict__ deg6,
                                             const float* __restrict__ attall,
                                             const float* __restrict__ bgall) {
  int r = blockIdx.y;
  unsigned short* Y = Yall + (long)r * MPAD * 512;
  const int* ssrc = ssrc6 + (long)r * EE;
  const float* att = attall + r * HC;
  const float* bg  = bgall + r * HC;
  int l = threadIdx.x & 63;
  int n = blockIdx.x * 4 + (threadIdx.x >> 6);
  if (n >= NN) return;
  const unsigned short* yb = Y + (long)n * 512;
  ushort4v xlv = *(const ushort4v*)(yb + 4 * l);
  ushort4v xrv = *(const ushort4v*)(yb + 256 + 4 * l);
  float xl[4], xr[4];
#pragma unroll
  for (int j = 0; j < 4; j++) { xl[j] = b2f(xlv[j]); xr[j] = b2f(xrv[j]); }
  float4 at4 = *(const float4*)(att + 4 * l);
  float at[4] = {at4.x, at4.y, at4.z, at4.w};
  float num[4] = {0.f, 0.f, 0.f, 0.f}, den = 0.f;
  // self loop
  {
    float lg = 0.f;
#pragma unroll
    for (int j = 0; j < 4; j++) {
      float e = xl[j] + xr[j];
      e = e > 0.f ? e : 0.2f * e;
      lg += at[j] * e;
    }
    lg += __shfl_xor(lg, 1); lg += __shfl_xor(lg, 2);
    lg += __shfl_xor(lg, 4); lg += __shfl_xor(lg, 8);
    float a = expf(lg);
    den += a;
#pragma unroll
    for (int j = 0; j < 4; j++) num[j] += a * xl[j];
  }
  int st = off6[(long)r * NN + n], cnt = deg6[(long)r * NN + n];
  int i = 0;
  for (; i + 2 <= cnt; i += 2) {   // 2-way unroll: two gathers in flight
    int s0 = ssrc[st + i], s1 = ssrc[st + i + 1];
    ushort4v v0 = *(const ushort4v*)(Y + (long)s0 * 512 + 4 * l);
    ushort4v v1 = *(const ushort4v*)(Y + (long)s1 * 512 + 4 * l);
    float x0[4], x1[4];
#pragma unroll
    for (int j = 0; j < 4; j++) { x0[j] = b2f(v0[j]); x1[j] = b2f(v1[j]); }
    float lg0 = 0.f, lg1 = 0.f;
#pragma unroll
    for (int j = 0; j < 4; j++) {
      float e0 = x0[j] + xr[j]; e0 = e0 > 0.f ? e0 : 0.2f * e0; lg0 += at[j] * e0;
      float e1 = x1[j] + xr[j]; e1 = e1 > 0.f ? e1 : 0.2f * e1; lg1 += at[j] * e1;
    }
    lg0 += __shfl_xor(lg0, 1); lg1 += __shfl_xor(lg1, 1);
    lg0 += __shfl_xor(lg0, 2); lg1 += __shfl_xor(lg1, 2);
    lg0 += __shfl_xor(lg0, 4); lg1 += __shfl_xor(lg1, 4);
    lg0 += __shfl_xor(lg0, 8); lg1 += __shfl_xor(lg1, 8);
    float a0 = expf(lg0), a1 = expf(lg1);
    den += a0 + a1;
#pragma unroll
    for (int j = 0; j < 4; j++) num[j] += a0 * x0[j] + a1 * x1[j];
  }
  if (i < cnt) {
    int s0 = ssrc[st + i];
    ushort4v v0 = *(const ushort4v*)(Y + (long)s0 * 512 + 4 * l);
    float x0[4];
#pragma unroll
    for (int j = 0; j < 4; j++) x0[j] = b2f(v0[j]);
    float lg = 0.f;
#pragma unroll
    for (int j = 0; j < 4; j++) {
      float e = x0[j] + xr[j];
      e = e > 0.f ? e : 0.2f * e;
      lg += at[j] * e;
    }
    lg += __shfl_xor(lg, 1); lg += __shfl_xor(lg, 2);
    lg += __shfl_xor(lg, 4); lg += __shfl_xor(lg, 8);
    float a = expf(lg);
    den += a;
#pragma unroll
    for (int j = 0; j < 4; j++) num[j] += a * x0[j];
  }
  float4 bg4 = *(const float4*)(bg + 4 * l);
  float bgj[4] = {bg4.x, bg4.y, bg4.z, bg4.w};
  ushort4v o;
  float inv = 1.f / (den + 1e-16f);
#pragma unroll
  for (int j = 0; j < 4; j++) o[j] = f2b(fmaxf(num[j] * inv + bgj[j], 0.f));
  *(ushort4v*)(Y + (long)n * 512 + 256 + 4 * l) = o;   // h1 over dead xr
}

// ---------- layer-1 combine: h2 = relu(sum_src Z1 + R1 + b1) -> Y[:,0:64] ----------
__global__ __launch_bounds__(256) void k_aggc1(const unsigned short* __restrict__ ZRall,
                                               unsigned short* __restrict__ Yall,
                                               const int* __restrict__ ssrc6,
                                               const int* __restrict__ off6,
                                               const int* __restrict__ deg6,
                                               const float* __restrict__ b1all) {
  int r = blockIdx.y;
  const unsigned short* ZR = ZRall + (long)r * MPAD * 128;
  unsigned short* Y = Yall + (long)r * MPAD * 512;
  const int* ssrc = ssrc6 + (long)r * EE;
  int l = threadIdx.x & 63;
  int n = blockIdx.x * 4 + (threadIdx.x >> 6);
  if (n >= NN) return;
  float acc = 0.f;
  int st = off6[(long)r * NN + n], cnt = deg6[(long)r * NN + n];
  int i = 0;
  for (; i + 4 <= cnt; i += 4) {
    int s0 = ssrc[st + i], s1 = ssrc[st + i + 1], s2 = ssrc[st + i + 2], s3 = ssrc[st + i + 3];
    acc += b2f(ZR[(long)s0 * 128 + l]) + b2f(ZR[(long)s1 * 128 + l]) +
           b2f(ZR[(long)s2 * 128 + l]) + b2f(ZR[(long)s3 * 128 + l]);
  }
  for (; i < cnt; i++) {
    int s = ssrc[st + i];
    acc += b2f(ZR[(long)s * 128 + l]);
  }
  float v = acc + b2f(ZR[(long)n * 128 + 64 + l]) + b1all[r * 64 + l];
  Y[(long)n * 512 + l] = f2b(fmaxf(v, 0.f));
}

// ---------- layer-2 combine: out = sum_src Z2 + R2 + b2 (f32 final) ----------
__global__ __launch_bounds__(256) void k_aggc2(const unsigned short* __restrict__ ZRall,
                                               float* __restrict__ out,
                                               const int* __restrict__ ssrc6,
                                               const int* __restrict__ off6,
                                               const int* __restrict__ deg6,
                                               const float* __restrict__ b2all) {
  int r = blockIdx.y;
  const unsigned short* ZR = ZRall + (long)r * MPAD * 128;
  const int* ssrc = ssrc6 + (long)r * EE;
  int l = threadIdx.x & 63;
  int n = blockIdx.x * 4 + (threadIdx.x >> 6);
  if (n >= NN) return;
  float acc = 0.f;
  int st = off6[(long)r * NN + n], cnt = deg6[(long)r * NN + n];
  int i = 0;
  for (; i + 4 <= cnt; i += 4) {
    int s0 = ssrc[st + i], s1 = ssrc[st + i + 1], s2 = ssrc[st + i + 2], s3 = ssrc[st + i + 3];
    acc += b2f(ZR[(long)s0 * 128 + l]) + b2f(ZR[(long)s1 * 128 + l]) +
           b2f(ZR[(long)s2 * 128 + l]) + b2f(ZR[(long)s3 * 128 + l]);
  }
  for (; i < cnt; i++) {
    int s = ssrc[st + i];
    acc += b2f(ZR[(long)s * 128 + l]);
  }
  float v = acc + b2f(ZR[(long)n * 128 + 64 + l]) + b2all[r * 64 + l];
  out[(long)n * (RREL * 64) + r * 64 + l] = v;
}

extern "C" void kernel_launch(void* const* d_in, const int* in_sizes, int n_in,
                              void* d_out, int out_size, void* d_ws, size_t ws_size,
                              hipStream_t stream) {
  (void)in_sizes; (void)n_in; (void)out_size;
  const float* x      = (const float*)d_in[0];
  const int*   ei     = (const int*)d_in[1];
  const float* Wl     = (const float*)d_in[2];
  const float* Wr     = (const float*)d_in[3];
  const float* att    = (const float*)d_in[4];
  const float* bg     = (const float*)d_in[5];
  const float* Wrel1  = (const float*)d_in[6];
  const float* Wroot1 = (const float*)d_in[7];
  const float* b1     = (const float*)d_in[8];
  const float* Wrel2  = (const float*)d_in[9];
  const float* Wroot2 = (const float*)d_in[10];
  const float* b2     = (const float*)d_in[11];
  float* out = (float*)d_out;

  char* ws = (char*)d_ws;
  size_t ofs = 0;
  auto alloc = [&](size_t bytes) {
    char* p = ws + ofs;
    ofs += (bytes + 255) & ~(size_t)255;
    return p;
  };
  unsigned short* Xb   = (unsigned short*)alloc((size_t)MPAD * DD * 2);
  unsigned short* Wt   = (unsigned short*)alloc((size_t)RREL * 512 * DD * 2);
  unsigned short* Bt1  = (unsigned short*)alloc((size_t)RREL * 128 * 256 * 2);
  unsigned short* Bt2  = (unsigned short*)alloc((size_t)RREL * 128 * 64 * 2);
  unsigned short* Yall = (unsigned short*)alloc((size_t)RREL * MPAD * 512 * 2);  // 308 MB
  unsigned short* ZR   = (unsigned short*)alloc((size_t)RREL * MPAD * 128 * 2);  // 77 MB
  int* deg6   = (int*)alloc((size_t)RREL * NN * 4);
  int* off6   = (int*)alloc((size_t)RREL * NN * 4);
  int* cur6   = (int*)alloc((size_t)RREL * NN * 4);
  int* bsum   = (int*)alloc((size_t)RREL * SCAN_B * 4);
  int* ssrc6  = (int*)alloc((size_t)RREL * EE * 4);
  if (ofs > ws_size) return;

  k_cvt_x<<<(int)((long)MPAD * DD / 8 / 256), 256, 0, stream>>>(x, Xb);
  k_repack_w<<<dim3(DD / 32, 512 / 32, RREL), 256, 0, stream>>>(Wl, Wr, Wt);
  k_repack_zr<<<(RREL * 128 * 256 + 255) / 256, 256, 0, stream>>>(Wrel1, Wroot1, Bt1, 256);
  k_repack_zr<<<(RREL * 128 * 64 + 255) / 256, 256, 0, stream>>>(Wrel2, Wroot2, Bt2, 64);
  hipMemsetAsync(deg6, 0, (size_t)RREL * NN * 4, stream);
  k_deg6<<<((long)RREL * EE + 255) / 256, 256, 0, stream>>>(ei, deg6);
  k_bsum<<<dim3(SCAN_B, RREL), 256, 0, stream>>>(deg6, bsum);
  k_bscan<<<1, 384, 0, stream>>>(bsum);
  k_boff<<<dim3(SCAN_B, RREL), 256, 0, stream>>>(deg6, bsum, off6, cur6);
  k_scatter6<<<((long)RREL * EE + 255) / 256, 256, 0, stream>>>(ei, cur6, ssrc6);

  // one fused 2-phase GEMM: all relations, all 3072 output columns
  k_gemm<<<dim3(196 * 12), 512, 0, stream>>>((const short*)Xb, (const short*)Wt, Yall);
  // GATv2 edge stage (h1 -> Y[:,256:512])
  k_gat<<<dim3(NN / 4, RREL), 256, 0, stream>>>(Yall, ssrc6, off6, deg6, att, bg);
  // layer 1: [Z1|R1] = h1 @ [Wrel1|Wroot1]; h2 = relu(agg Z1 + R1 + b1) -> Y[:,0:64]
  k_zr<256><<<dim3(MPAD / 128, RREL), 256, 0, stream>>>(Yall, 512, 256, Bt1, ZR);
  k_aggc1<<<dim3(NN / 4, RREL), 256, 0, stream>>>(ZR, Yall, ssrc6, off6, deg6, b1);
  // layer 2: [Z2|R2] = h2 @ [Wrel2|Wroot2]; out = agg Z2 + R2 + b2
  k_zr<64><<<dim3(MPAD / 128, RREL), 256, 0, stream>>>(Yall, 512, 0, Bt2, ZR);
  k_aggc2<<<dim3(NN / 4, RREL), 256, 0, stream>>>(ZR, out, ssrc6, off6, deg6, b2);
}

// Round 6
// 1125.965 us; speedup vs baseline: 1.1423x; 1.0143x over previous
//
#include <hip/hip_runtime.h>
#include <hip/hip_bf16.h>
#include <math.h>

#define RREL 6
#define NN   50000
#define EE   200000
#define DD   768
#define HH   4
#define CC   64
#define HC   256
#define OO   64
#define MPAD 50176    // 196 * 256
#define SCAN_B 49     // ceil(NN/1024)
#define NT   12       // 768 / 64 K-tiles

typedef __attribute__((ext_vector_type(8))) short short8;
typedef __attribute__((ext_vector_type(4))) float f32x4;
typedef __attribute__((ext_vector_type(8))) unsigned short ushort8v;
typedef __attribute__((ext_vector_type(4))) unsigned short ushort4v;

__device__ __forceinline__ float b2f(unsigned short u) {
  return __uint_as_float(((unsigned)u) << 16);
}
__device__ __forceinline__ unsigned short f2b(float f) {
  __hip_bfloat16 h = __float2bfloat16(f);
  unsigned short u;
  __builtin_memcpy(&u, &h, 2);
  return u;
}

// global_load_lds, 16B/lane, wave-uniform LDS base + lane*16
__device__ __forceinline__ void gload16(const void* g, void* s) {
  typedef __attribute__((address_space(1))) void gvoid;
  typedef __attribute__((address_space(3))) void svoid;
  __builtin_amdgcn_global_load_lds((gvoid*)(unsigned long long)g,
                                   (svoid*)(unsigned long long)s, 16, 0, 0);
}

// ---------- x -> bf16 (8 elems/thread) ----------
__global__ __launch_bounds__(256) void k_cvt_x(const float* __restrict__ x,
                                               unsigned short* __restrict__ xb) {
  long t = (long)blockIdx.x * 256 + threadIdx.x;
  long base = t * 8;
  int row = (int)(base / DD);
  ushort8v o;
  if (row < NN) {
    float4 a = *(const float4*)(x + base);
    float4 b = *(const float4*)(x + base + 4);
    o[0] = f2b(a.x); o[1] = f2b(a.y); o[2] = f2b(a.z); o[3] = f2b(a.w);
    o[4] = f2b(b.x); o[5] = f2b(b.y); o[6] = f2b(b.z); o[7] = f2b(b.w);
  } else {
    o = (ushort8v)0;
  }
  *(ushort8v*)(xb + base) = o;
}

// ---------- LDS-tiled transpose: Wl|Wr [768][256] -> Wt[r*512+j][768] bf16 ----------
__global__ __launch_bounds__(256) void k_repack_w(const float* __restrict__ Wl,
                                                  const float* __restrict__ Wr,
                                                  unsigned short* __restrict__ Wt) {
  __shared__ float t[32][33];
  int k0 = blockIdx.x * 32, j0 = blockIdx.y * 32, r = blockIdx.z;
  int tx = threadIdx.x & 31, ty = threadIdx.x >> 5;
#pragma unroll
  for (int s = 0; s < 4; s++) {
    int k = k0 + ty + 8 * s, j = j0 + tx;
    float v = (j < HC) ? Wl[((long)r * DD + k) * HC + j]
                       : Wr[((long)r * DD + k) * HC + (j - HC)];
    t[ty + 8 * s][tx] = v;
  }
  __syncthreads();
#pragma unroll
  for (int s = 0; s < 4; s++) {
    int j = j0 + ty + 8 * s, k = k0 + tx;
    Wt[((long)r * 512 + j) * DD + k] = f2b(t[tx][ty + 8 * s]);
  }
}

// ---------- repack [Wrel;Wroot] -> Bt[r][128][K] bf16 (cols 0-63 = rel, 64-127 = root) -
__global__ void k_repack_zr(const float* __restrict__ Wrel, const float* __restrict__ Wroot,
                            unsigned short* __restrict__ Bt, int K) {
  int idx = blockIdx.x * blockDim.x + threadIdx.x;
  if (idx >= RREL * 128 * K) return;
  int k = idx % K;
  int j = (idx / K) % 128;
  int r = idx / (128 * K);
  float v = (j < 64) ? Wrel[((long)r * K + k) * 64 + j]
                     : Wroot[((long)r * K + k) * 64 + (j - 64)];
  Bt[idx] = f2b(v);
}

// ---------- fused 256x256 GEMM, 2-phase/tile: Yall[r][MPAD][512] = Xb @ Wt_all^T ------
// B fragment mapping: lane l16 holds C-cols wn+4*l16+{0..3} (B rows 4*l16+j'), so the
// epilogue packs 4 same-row bf16 -> one dwordx2 (full-line 128B wave segments; stores
// 128->32 per thread).  B LDS swizzle accordingly keyed on (row>>2)&7 (read-side
// expression unchanged, 2-way banks).  A side and MFMA schedule identical to R5.
#define STAGE_A(HALF, TT)                                                              \
  if ((TT) < NT) {                                                                     \
    long ko = (long)(TT) * 128;                                                        \
    char* db = ldsA + (((TT) & 1) << 15);                                              \
    gload16(AgB + (long)((HALF) * 64 + rA) * 1536 + ko + xcol,                         \
            db + ((HALF) * 64) * 128 + wave * 1024);                                   \
    gload16(AgB + (long)((HALF) * 64 + 128 + rA) * 1536 + ko + xcol,                   \
            db + ((HALF) * 64 + 128) * 128 + wave * 1024);                             \
  }

#define STAGE_B(HALF, TT)                                                              \
  if ((TT) < NT) {                                                                     \
    long ko = (long)(TT) * 128;                                                        \
    char* db = ldsB + (((TT) & 1) << 15);                                              \
    gload16(BgB + (long)(rb0 + (HALF) * 32 + lane8) * 1536 + ko + xcolB,               \
            db + (rb0 + (HALF) * 32) * 128);                                           \
    gload16(BgB + (long)(rb1 + (HALF) * 32 + lane8) * 1536 + ko + xcolB,               \
            db + (rb1 + (HALF) * 32) * 128);                                           \
  }

// one C-quadrant (4x2 fragments) x K=64 using held A-set PA and pb[NH]
#define MMQ(PA, AOFF, NH)                                                              \
  do {                                                                                 \
    _Pragma("unroll") for (int fi = 0; fi < 4; ++fi)                                   \
    _Pragma("unroll") for (int fj = 0; fj < 2; ++fj) {                                 \
      f32x4 c = acc[(AOFF) + fi][(NH) * 2 + fj];                                       \
      c = __builtin_amdgcn_mfma_f32_16x16x32_bf16(PA[fi][0], pb[NH][fj][0], c, 0, 0, 0);\
      c = __builtin_amdgcn_mfma_f32_16x16x32_bf16(PA[fi][1], pb[NH][fj][1], c, 0, 0, 0);\
      acc[(AOFF) + fi][(NH) * 2 + fj] = c;                                             \
    }                                                                                  \
  } while (0)

__global__ __launch_bounds__(512, 2) void k_gemm(const short* __restrict__ A,
                                                 const short* __restrict__ Bt,
                                                 unsigned short* __restrict__ Yall) {
  __shared__ __align__(16) char ldsA[65536];   // 2 bufs x 256 rows x 128 B
  __shared__ __align__(16) char ldsB[65536];
  int tid = threadIdx.x;
  int wgid = blockIdx.x;                       // 2352 = 196*12, 2352 % 8 == 0
  int swz = (wgid & 7) * 294 + (wgid >> 3);    // bijective XCD swizzle
  int bm = swz / 12, bn = swz % 12;            // bn fastest: A panel L2-resident per XCD
  int lane = tid & 63, wave = tid >> 6;
  int warp_m = wave >> 2, warp_n = wave & 3;
  int wm = warp_m * 128, wn = warp_n * 64;
  int l16 = lane & 15, quad = lane >> 4;
  int gm0 = bm * 256;
  const char* AgB = (const char*)A + (long)gm0 * 1536;
  const char* BgB = (const char*)Bt + (long)bn * 256 * 1536;
  int rA = tid >> 3;                           // 0..63: staged row within 64-row issue
  int lane8 = lane >> 3;
  long xcol  = (long)(((tid & 7) ^ (rA & 7)) * 16);   // A pre-swizzle: slot ^ (row&7)
  long xcolB = (long)(((tid & 7) ^ (2 * (wave & 3) + (lane >> 5))) * 16); // B: slot ^ ((row>>2)&7)
  int rb0 = (wave >> 2) * 64 + (wave & 3) * 8;        // B stage row base (wave-uniform)
  int rb1 = rb0 + 128;
  int s0 = (quad ^ (l16 & 7)) * 16, s1 = s0 ^ 64;     // swizzled ds_read slot bytes
  f32x4 acc[8][4] = {};

  // prologue: tile0 fully + tile1 X halves; wait leaves 2 half-tiles (4 loads) in flight
  STAGE_A(0, 0); STAGE_B(0, 0); STAGE_A(1, 0); STAGE_B(1, 0);
  STAGE_A(0, 1); STAGE_B(0, 1);
  asm volatile("s_waitcnt vmcnt(4)" ::: "memory");
  __builtin_amdgcn_s_barrier();

  for (int t = 0; t < NT; ++t) {
    int bo = (t & 1) << 15;
    const char* Ard = ldsA + bo + (wm + l16) * 128;
    const char* Brd = ldsB + bo + (wn + 4 * l16) * 128;   // lane holds 4 consecutive B rows
    short8 pa0[4][2], pa1[4][2], pb[2][2][2];
    // ---- phase A: stage Y halves of t+1; read pa0 + ALL pb; 2 MFMA quadrants ----
    STAGE_A(1, t + 1);
    STAGE_B(1, t + 1);
#pragma unroll
    for (int fi = 0; fi < 4; ++fi) {
      pa0[fi][0] = *(const short8*)(Ard + (fi * 16) * 128 + s0);
      pa0[fi][1] = *(const short8*)(Ard + (fi * 16) * 128 + s1);
    }
#pragma unroll
    for (int nh = 0; nh < 2; ++nh)
#pragma unroll
      for (int fj = 0; fj < 2; ++fj) {
        pb[nh][fj][0] = *(const short8*)(Brd + (nh * 2 + fj) * 128 + s0);
        pb[nh][fj][1] = *(const short8*)(Brd + (nh * 2 + fj) * 128 + s1);
      }
    __builtin_amdgcn_s_barrier();
    asm volatile("s_waitcnt lgkmcnt(0)" ::: "memory");
    __builtin_amdgcn_s_setprio(1);
    MMQ(pa0, 0, 0);
    __builtin_amdgcn_s_setprio(0);
    // pa1 reads issue here; their latency hides under MMQ(pa0,0,1)'s 16 MFMA
#pragma unroll
    for (int fi = 0; fi < 4; ++fi) {
      pa1[fi][0] = *(const short8*)(Ard + ((64 + fi * 16)) * 128 + s0);
      pa1[fi][1] = *(const short8*)(Ard + ((64 + fi * 16)) * 128 + s1);
    }
    __builtin_amdgcn_s_setprio(1);
    MMQ(pa0, 0, 1);
    __builtin_amdgcn_s_setprio(0);
    __builtin_amdgcn_s_barrier();
    // ---- phase B: stage X halves of t+2 (freed above); 2 MFMA quadrants ----
    STAGE_A(0, t + 2);
    STAGE_B(0, t + 2);
    asm volatile("s_waitcnt lgkmcnt(0)" ::: "memory");
    __builtin_amdgcn_s_setprio(1);
    MMQ(pa1, 4, 0);
    MMQ(pa1, 4, 1);
    __builtin_amdgcn_s_setprio(0);
    if (t < NT - 2)       asm volatile("s_waitcnt vmcnt(4)" ::: "memory");
    else if (t == NT - 2) asm volatile("s_waitcnt vmcnt(0)" ::: "memory");
    __builtin_amdgcn_s_barrier();
  }

  // epilogue: thread holds cols cb..cb+3 for 32 rows -> 32 packed dwordx2 stores.
  int rel = bn >> 1;
  unsigned short* Yr = Yall + (long)rel * MPAD * 512;
  int cb = (bn & 1) * 256 + wn + 4 * l16;
#pragma unroll
  for (int i = 0; i < 8; ++i) {
    int rowb = gm0 + wm + (i >> 2) * 64 + (i & 3) * 16 + quad * 4;
#pragma unroll
    for (int reg = 0; reg < 4; ++reg) {
      uint2 v;
      v.x = (unsigned)f2b(acc[i][0][reg]) | ((unsigned)f2b(acc[i][1][reg]) << 16);
      v.y = (unsigned)f2b(acc[i][2][reg]) | ((unsigned)f2b(acc[i][3][reg]) << 16);
      *(uint2*)(Yr + (long)(rowb + reg) * 512 + cb) = v;
    }
  }
}

// ---------- batched 128-col MFMA GEMM: ZR[r][MPAD][128] = A @ Bt^T (no bias) ----------
// A is rel-strided bf16 with row stride lda and column offset aoff.
template <int K>
__global__ __launch_bounds__(256) void k_zr(const unsigned short* __restrict__ Abase,
                                            long lda, long aoff,
                                            const unsigned short* __restrict__ Btall,
                                            unsigned short* __restrict__ ZRall) {
  __shared__ __align__(16) short As[128 * 32];
  __shared__ __align__(16) short Bs[128 * 32];
  int tid = threadIdx.x;
  int bm = blockIdx.x, r = blockIdx.y;
  const unsigned short* A  = Abase + (long)r * MPAD * lda + aoff;
  const unsigned short* Bt = Btall + (long)r * 128 * K;
  unsigned short* ZR = ZRall + (long)r * MPAD * 128;
  int lane = tid & 63, wave = tid >> 6;
  int quad = lane >> 4, l16 = lane & 15;
  f32x4 acc[2][8] = {};
  const unsigned short* Ag = A + (long)bm * 128 * lda;
  int lr = lane >> 2, lc = (lane & 3) * 8;
  const unsigned short* ga0 = Ag + (long)(wave * 16 + lr) * lda + lc;
  const unsigned short* ga1 = Ag + (long)(64 + wave * 16 + lr) * lda + lc;
  const unsigned short* gb0 = Bt + (long)(wave * 16 + lr) * K + lc;
  const unsigned short* gb1 = Bt + (long)(64 + wave * 16 + lr) * K + lc;
  short* la0 = &As[(wave * 16) * 32];
  short* la1 = &As[(64 + wave * 16) * 32];
  short* lb0 = &Bs[(wave * 16) * 32];
  short* lb1 = &Bs[(64 + wave * 16) * 32];
  for (int k0 = 0; k0 < K; k0 += 32) {
    gload16(ga0 + k0, la0);
    gload16(ga1 + k0, la1);
    gload16(gb0 + k0, lb0);
    gload16(gb1 + k0, lb1);
    __syncthreads();
    short8 af[2], bf[8];
#pragma unroll
    for (int i = 0; i < 2; i++) af[i] = *(const short8*)&As[(wave * 32 + i * 16 + l16) * 32 + quad * 8];
#pragma unroll
    for (int j = 0; j < 8; j++) bf[j] = *(const short8*)&Bs[(j * 16 + l16) * 32 + quad * 8];
#pragma unroll
    for (int i = 0; i < 2; i++)
#pragma unroll
      for (int j = 0; j < 8; j++)
        acc[i][j] = __builtin_amdgcn_mfma_f32_16x16x32_bf16(af[i], bf[j], acc[i][j], 0, 0, 0);
    __syncthreads();
  }
#pragma unroll
  for (int i = 0; i < 2; i++)
#pragma unroll
    for (int j = 0; j < 8; j++)
#pragma unroll
      for (int reg = 0; reg < 4; reg++) {
        int row = bm * 128 + wave * 32 + i * 16 + quad * 4 + reg;
        int col = j * 16 + l16;
        ZR[(long)row * 128 + col] = f2b(acc[i][j][reg]);
      }
}

// ---------- batched CSR build ----------
__global__ void k_deg6(const int* __restrict__ ei, int* __restrict__ deg6) {
  long e = (long)blockIdx.x * blockDim.x + threadIdx.x;
  if (e >= (long)RREL * EE) return;
  int r = e / EE, i = e % EE;
  int t = ei[(long)r * 2 * EE + EE + i];
  atomicAdd(&deg6[(long)r * NN + t], 1);
}

__global__ __launch_bounds__(256) void k_bsum(const int* __restrict__ deg6, int* __restrict__ bsum) {
  int r = blockIdx.y, b = blockIdx.x, tid = threadIdx.x;
  const int* deg = deg6 + (long)r * NN;
  int i0 = b * 1024 + tid * 4;
  int s = 0;
#pragma unroll
  for (int j = 0; j < 4; j++) { int i = i0 + j; if (i < NN) s += deg[i]; }
#pragma unroll
  for (int m = 1; m < 64; m <<= 1) s += __shfl_xor(s, m);
  __shared__ int ws[4];
  if ((tid & 63) == 0) ws[tid >> 6] = s;
  __syncthreads();
  if (tid == 0) bsum[r * SCAN_B + b] = ws[0] + ws[1] + ws[2] + ws[3];
}

__global__ void k_bscan(int* __restrict__ bsum) {   // 1 block, 384 thr = 6 waves
  int w = threadIdx.x >> 6, l = threadIdx.x & 63;
  int v = (l < SCAN_B) ? bsum[w * SCAN_B + l] : 0;
  int incl = v;
#pragma unroll
  for (int d = 1; d < 64; d <<= 1) { int t = __shfl_up(incl, d); if (l >= d) incl += t; }
  if (l < SCAN_B) bsum[w * SCAN_B + l] = incl - v;   // exclusive
}

__global__ __launch_bounds__(256) void k_boff(const int* __restrict__ deg6, const int* __restrict__ bsum,
                                              int* __restrict__ off6, int* __restrict__ cur6) {
  int r = blockIdx.y, b = blockIdx.x, tid = threadIdx.x;
  const int* deg = deg6 + (long)r * NN;
  int i0 = b * 1024 + tid * 4;
  int v[4], s = 0;
#pragma unroll
  for (int j = 0; j < 4; j++) { int i = i0 + j; v[j] = (i < NN) ? deg[i] : 0; s += v[j]; }
  int l = tid & 63, wv = tid >> 6;
  int incl = s;
#pragma unroll
  for (int d = 1; d < 64; d <<= 1) { int t = __shfl_up(incl, d); if (l >= d) incl += t; }
  __shared__ int ws[4];
  if (l == 63) ws[wv] = incl;
  __syncthreads();
  int pre = incl - s;
  for (int k = 0; k < wv; k++) pre += ws[k];
  pre += bsum[r * SCAN_B + b];
  int e0 = pre;
#pragma unroll
  for (int j = 0; j < 4; j++) {
    int i = i0 + j;
    if (i < NN) { off6[(long)r * NN + i] = e0; cur6[(long)r * NN + i] = e0; }
    e0 += v[j];
  }
}

__global__ void k_scatter6(const int* __restrict__ ei, int* __restrict__ cur6,
                           int* __restrict__ ssrc6) {
  long e = (long)blockIdx.x * blockDim.x + threadIdx.x;
  if (e >= (long)RREL * EE) return;
  int r = e / EE, i = e % EE;
  int src = ei[(long)r * 2 * EE + i];
  int t   = ei[(long)r * 2 * EE + EE + i];
  int p = atomicAdd(&cur6[(long)r * NN + t], 1);
  ssrc6[(long)r * EE + p] = src;
}

// ---------- batched fused GATv2 (blockIdx.y = r); h1 overwrites Y[:,256:512] ----------
__global__ __launch_bounds__(256) void k_gat(unsigned short* __restrict__ Yall,
                                             const int* __restrict__ ssrc6,
                                             const int* __restrict__ off6, const int* __restrict__ deg6,
                                             const float* __restrict__ attall,
                                             const float* __restrict__ bgall) {
  int r = blockIdx.y;
  unsigned short* Y = Yall + (long)r * MPAD * 512;
  const int* ssrc = ssrc6 + (long)r * EE;
  const float* att = attall + r * HC;
  const float* bg  = bgall + r * HC;
  int l = threadIdx.x & 63;
  int n = blockIdx.x * 4 + (threadIdx.x >> 6);
  if (n >= NN) return;
  const unsigned short* yb = Y + (long)n * 512;
  ushort4v xlv = *(const ushort4v*)(yb + 4 * l);
  ushort4v xrv = *(const ushort4v*)(yb + 256 + 4 * l);
  float xl[4], xr[4];
#pragma unroll
  for (int j = 0; j < 4; j++) { xl[j] = b2f(xlv[j]); xr[j] = b2f(xrv[j]); }
  float4 at4 = *(const float4*)(att + 4 * l);
  float at[4] = {at4.x, at4.y, at4.z, at4.w};
  float num[4] = {0.f, 0.f, 0.f, 0.f}, den = 0.f;
  // self loop
  {
    float lg = 0.f;
#pragma unroll
    for (int j = 0; j < 4; j++) {
      float e = xl[j] + xr[j];
      e = e > 0.f ? e : 0.2f * e;
      lg += at[j] * e;
    }
    lg += __shfl_xor(lg, 1); lg += __shfl_xor(lg, 2);
    lg += __shfl_xor(lg, 4); lg += __shfl_xor(lg, 8);
    float a = expf(lg);
    den += a;
#pragma unroll
    for (int j = 0; j < 4; j++) num[j] += a * xl[j];
  }
  int st = off6[(long)r * NN + n], cnt = deg6[(long)r * NN + n];
  int i = 0;
  for (; i + 4 <= cnt; i += 4) {   // 4-way unroll: four gathers in flight
    int s0 = ssrc[st + i], s1 = ssrc[st + i + 1];
    int s2 = ssrc[st + i + 2], s3 = ssrc[st + i + 3];
    ushort4v v0 = *(const ushort4v*)(Y + (long)s0 * 512 + 4 * l);
    ushort4v v1 = *(const ushort4v*)(Y + (long)s1 * 512 + 4 * l);
    ushort4v v2 = *(const ushort4v*)(Y + (long)s2 * 512 + 4 * l);
    ushort4v v3 = *(const ushort4v*)(Y + (long)s3 * 512 + 4 * l);
    float x0[4], x1[4], x2[4], x3[4];
#pragma unroll
    for (int j = 0; j < 4; j++) {
      x0[j] = b2f(v0[j]); x1[j] = b2f(v1[j]); x2[j] = b2f(v2[j]); x3[j] = b2f(v3[j]);
    }
    float lg0 = 0.f, lg1 = 0.f, lg2 = 0.f, lg3 = 0.f;
#pragma unroll
    for (int j = 0; j < 4; j++) {
      float e0 = x0[j] + xr[j]; e0 = e0 > 0.f ? e0 : 0.2f * e0; lg0 += at[j] * e0;
      float e1 = x1[j] + xr[j]; e1 = e1 > 0.f ? e1 : 0.2f * e1; lg1 += at[j] * e1;
      float e2 = x2[j] + xr[j]; e2 = e2 > 0.f ? e2 : 0.2f * e2; lg2 += at[j] * e2;
      float e3 = x3[j] + xr[j]; e3 = e3 > 0.f ? e3 : 0.2f * e3; lg3 += at[j] * e3;
    }
    lg0 += __shfl_xor(lg0, 1); lg1 += __shfl_xor(lg1, 1); lg2 += __shfl_xor(lg2, 1); lg3 += __shfl_xor(lg3, 1);
    lg0 += __shfl_xor(lg0, 2); lg1 += __shfl_xor(lg1, 2); lg2 += __shfl_xor(lg2, 2); lg3 += __shfl_xor(lg3, 2);
    lg0 += __shfl_xor(lg0, 4); lg1 += __shfl_xor(lg1, 4); lg2 += __shfl_xor(lg2, 4); lg3 += __shfl_xor(lg3, 4);
    lg0 += __shfl_xor(lg0, 8); lg1 += __shfl_xor(lg1, 8); lg2 += __shfl_xor(lg2, 8); lg3 += __shfl_xor(lg3, 8);
    float a0 = expf(lg0), a1 = expf(lg1), a2 = expf(lg2), a3 = expf(lg3);
    den += (a0 + a1) + (a2 + a3);
#pragma unroll
    for (int j = 0; j < 4; j++) num[j] += (a0 * x0[j] + a1 * x1[j]) + (a2 * x2[j] + a3 * x3[j]);
  }
  for (; i + 2 <= cnt; i += 2) {
    int s0 = ssrc[st + i], s1 = ssrc[st + i + 1];
    ushort4v v0 = *(const ushort4v*)(Y + (long)s0 * 512 + 4 * l);
    ushort4v v1 = *(const ushort4v*)(Y + (long)s1 * 512 + 4 * l);
    float x0[4], x1[4];
#pragma unroll
    for (int j = 0; j < 4; j++) { x0[j] = b2f(v0[j]); x1[j] = b2f(v1[j]); }
    float lg0 = 0.f, lg1 = 0.f;
#pragma unroll
    for (int j = 0; j < 4; j++) {
      float e0 = x0[j] + xr[j]; e0 = e0 > 0.f ? e0 : 0.2f * e0; lg0 += at[j] * e0;
      float e1 = x1[j] + xr[j]; e1 = e1 > 0.f ? e1 : 0.2f * e1; lg1 += at[j] * e1;
    }
    lg0 += __shfl_xor(lg0, 1); lg1 += __shfl_xor(lg1, 1);
    lg0 += __shfl_xor(lg0, 2); lg1 += __shfl_xor(lg1, 2);
    lg0 += __shfl_xor(lg0, 4); lg1 += __shfl_xor(lg1, 4);
    lg0 += __shfl_xor(lg0, 8); lg1 += __shfl_xor(lg1, 8);
    float a0 = expf(lg0), a1 = expf(lg1);
    den += a0 + a1;
#pragma unroll
    for (int j = 0; j < 4; j++) num[j] += a0 * x0[j] + a1 * x1[j];
  }
  if (i < cnt) {
    int s0 = ssrc[st + i];
    ushort4v v0 = *(const ushort4v*)(Y + (long)s0 * 512 + 4 * l);
    float x0[4];
#pragma unroll
    for (int j = 0; j < 4; j++) x0[j] = b2f(v0[j]);
    float lg = 0.f;
#pragma unroll
    for (int j = 0; j < 4; j++) {
      float e = x0[j] + xr[j];
      e = e > 0.f ? e : 0.2f * e;
      lg += at[j] * e;
    }
    lg += __shfl_xor(lg, 1); lg += __shfl_xor(lg, 2);
    lg += __shfl_xor(lg, 4); lg += __shfl_xor(lg, 8);
    float a = expf(lg);
    den += a;
#pragma unroll
    for (int j = 0; j < 4; j++) num[j] += a * x0[j];
  }
  float4 bg4 = *(const float4*)(bg + 4 * l);
  float bgj[4] = {bg4.x, bg4.y, bg4.z, bg4.w};
  ushort4v o;
  float inv = 1.f / (den + 1e-16f);
#pragma unroll
  for (int j = 0; j < 4; j++) o[j] = f2b(fmaxf(num[j] * inv + bgj[j], 0.f));
  *(ushort4v*)(Y + (long)n * 512 + 256 + 4 * l) = o;   // h1 over dead xr
}

// ---------- layer-1 combine: h2 = relu(sum_src Z1 + R1 + b1) -> Y[:,0:64] ----------
__global__ __launch_bounds__(256) void k_aggc1(const unsigned short* __restrict__ ZRall,
                                               unsigned short* __restrict__ Yall,
                                               const int* __restrict__ ssrc6,
                                               const int* __restrict__ off6,
                                               const int* __restrict__ deg6,
                                               const float* __restrict__ b1all) {
  int r = blockIdx.y;
  const unsigned short* ZR = ZRall + (long)r * MPAD * 128;
  unsigned short* Y = Yall + (long)r * MPAD * 512;
  const int* ssrc = ssrc6 + (long)r * EE;
  int l = threadIdx.x & 63;
  int n = blockIdx.x * 4 + (threadIdx.x >> 6);
  if (n >= NN) return;
  float acc = 0.f;
  int st = off6[(long)r * NN + n], cnt = deg6[(long)r * NN + n];
  int i = 0;
  for (; i + 4 <= cnt; i += 4) {
    int s0 = ssrc[st + i], s1 = ssrc[st + i + 1], s2 = ssrc[st + i + 2], s3 = ssrc[st + i + 3];
    acc += b2f(ZR[(long)s0 * 128 + l]) + b2f(ZR[(long)s1 * 128 + l]) +
           b2f(ZR[(long)s2 * 128 + l]) + b2f(ZR[(long)s3 * 128 + l]);
  }
  for (; i < cnt; i++) {
    int s = ssrc[st + i];
    acc += b2f(ZR[(long)s * 128 + l]);
  }
  float v = acc + b2f(ZR[(long)n * 128 + 64 + l]) + b1all[r * 64 + l];
  Y[(long)n * 512 + l] = f2b(fmaxf(v, 0.f));
}

// ---------- layer-2 combine: out = sum_src Z2 + R2 + b2 (f32 final) ----------
__global__ __launch_bounds__(256) void k_aggc2(const unsigned short* __restrict__ ZRall,
                                               float* __restrict__ out,
                                               const int* __restrict__ ssrc6,
                                               const int* __restrict__ off6,
                                               const int* __restrict__ deg6,
                                               const float* __restrict__ b2all) {
  int r = blockIdx.y;
  const unsigned short* ZR = ZRall + (long)r * MPAD * 128;
  const int* ssrc = ssrc6 + (long)r * EE;
  int l = threadIdx.x & 63;
  int n = blockIdx.x * 4 + (threadIdx.x >> 6);
  if (n >= NN) return;
  float acc = 0.f;
  int st = off6[(long)r * NN + n], cnt = deg6[(long)r * NN + n];
  int i = 0;
  for (; i + 4 <= cnt; i += 4) {
    int s0 = ssrc[st + i], s1 = ssrc[st + i + 1], s2 = ssrc[st + i + 2], s3 = ssrc[st + i + 3];
    acc += b2f(ZR[(long)s0 * 128 + l]) + b2f(ZR[(long)s1 * 128 + l]) +
           b2f(ZR[(long)s2 * 128 + l]) + b2f(ZR[(long)s3 * 128 + l]);
  }
  for (; i < cnt; i++) {
    int s = ssrc[st + i];
    acc += b2f(ZR[(long)s * 128 + l]);
  }
  float v = acc + b2f(ZR[(long)n * 128 + 64 + l]) + b2all[r * 64 + l];
  out[(long)n * (RREL * 64) + r * 64 + l] = v;
}

extern "C" void kernel_launch(void* const* d_in, const int* in_sizes, int n_in,
                              void* d_out, int out_size, void* d_ws, size_t ws_size,
                              hipStream_t stream) {
  (void)in_sizes; (void)n_in; (void)out_size;
  const float* x      = (const float*)d_in[0];
  const int*   ei     = (const int*)d_in[1];
  const float* Wl     = (const float*)d_in[2];
  const float* Wr     = (const float*)d_in[3];
  const float* att    = (const float*)d_in[4];
  const float* bg     = (const float*)d_in[5];
  const float* Wrel1  = (const float*)d_in[6];
  const float* Wroot1 = (const float*)d_in[7];
  const float* b1     = (const float*)d_in[8];
  const float* Wrel2  = (const float*)d_in[9];
  const float* Wroot2 = (const float*)d_in[10];
  const float* b2     = (const float*)d_in[11];
  float* out = (float*)d_out;

  char* ws = (char*)d_ws;
  size_t ofs = 0;
  auto alloc = [&](size_t bytes) {
    char* p = ws + ofs;
    ofs += (bytes + 255) & ~(size_t)255;
    return p;
  };
  unsigned short* Xb   = (unsigned short*)alloc((size_t)MPAD * DD * 2);
  unsigned short* Wt   = (unsigned short*)alloc((size_t)RREL * 512 * DD * 2);
  unsigned short* Bt1  = (unsigned short*)alloc((size_t)RREL * 128 * 256 * 2);
  unsigned short* Bt2  = (unsigned short*)alloc((size_t)RREL * 128 * 64 * 2);
  unsigned short* Yall = (unsigned short*)alloc((size_t)RREL * MPAD * 512 * 2);  // 308 MB
  unsigned short* ZR   = (unsigned short*)alloc((size_t)RREL * MPAD * 128 * 2);  // 77 MB
  int* deg6   = (int*)alloc((size_t)RREL * NN * 4);
  int* off6   = (int*)alloc((size_t)RREL * NN * 4);
  int* cur6   = (int*)alloc((size_t)RREL * NN * 4);
  int* bsum   = (int*)alloc((size_t)RREL * SCAN_B * 4);
  int* ssrc6  = (int*)alloc((size_t)RREL * EE * 4);
  if (ofs > ws_size) return;

  k_cvt_x<<<(int)((long)MPAD * DD / 8 / 256), 256, 0, stream>>>(x, Xb);
  k_repack_w<<<dim3(DD / 32, 512 / 32, RREL), 256, 0, stream>>>(Wl, Wr, Wt);
  k_repack_zr<<<(RREL * 128 * 256 + 255) / 256, 256, 0, stream>>>(Wrel1, Wroot1, Bt1, 256);
  k_repack_zr<<<(RREL * 128 * 64 + 255) / 256, 256, 0, stream>>>(Wrel2, Wroot2, Bt2, 64);
  hipMemsetAsync(deg6, 0, (size_t)RREL * NN * 4, stream);
  k_deg6<<<((long)RREL * EE + 255) / 256, 256, 0, stream>>>(ei, deg6);
  k_bsum<<<dim3(SCAN_B, RREL), 256, 0, stream>>>(deg6, bsum);
  k_bscan<<<1, 384, 0, stream>>>(bsum);
  k_boff<<<dim3(SCAN_B, RREL), 256, 0, stream>>>(deg6, bsum, off6, cur6);
  k_scatter6<<<((long)RREL * EE + 255) / 256, 256, 0, stream>>>(ei, cur6, ssrc6);

  // one fused 2-phase GEMM: all relations, all 3072 output columns
  k_gemm<<<dim3(196 * 12), 512, 0, stream>>>((const short*)Xb, (const short*)Wt, Yall);
  // GATv2 edge stage (h1 -> Y[:,256:512])
  k_gat<<<dim3(NN / 4, RREL), 256, 0, stream>>>(Yall, ssrc6, off6, deg6, att, bg);
  // layer 1: [Z1|R1] = h1 @ [Wrel1|Wroot1]; h2 = relu(agg Z1 + R1 + b1) -> Y[:,0:64]
  k_zr<256><<<dim3(MPAD / 128, RREL), 256, 0, stream>>>(Yall, 512, 256, Bt1, ZR);
  k_aggc1<<<dim3(NN / 4, RREL), 256, 0, stream>>>(ZR, Yall, ssrc6, off6, deg6, b1);
  // layer 2: [Z2|R2] = h2 @ [Wrel2|Wroot2]; out = agg Z2 + R2 + b2
  k_zr<64><<<dim3(MPAD / 128, RREL), 256, 0, stream>>>(Yall, 512, 0, Bt2, ZR);
  k_aggc2<<<dim3(NN / 4, RREL), 256, 0, stream>>>(ZR, out, ssrc6, off6, deg6, b2);
}